// Round 1
// baseline (898.749 us; speedup 1.0000x reference)
//
#include <hip/hip_runtime.h>
#include <math.h>

// Problem constants
// B=2, S=4096 (=16^3), H=4, D=32, C=64, HID=128, 3*HID=384, SCALE=16
#define SCALE_F 16.0f

// ws layout (floats):
//  q: [B*H*D][S] = [256][4096]   offset 0
//  k: same                        offset 1M floats
//  v: same                        offset 2M floats
//  o: [B*S][128]                  offset 3M floats
// total 4M floats = 16 MB

// ---------------------------------------------------------------------------
// Kernel 1: qkv = input @ w_qkv, scattered into q/k/v in [b][h][d][s] layout
// grid: 128 s-tiles * 6 ch-tiles = 768 blocks, 256 threads
__global__ __launch_bounds__(256) void qkv_kernel(const float* __restrict__ in,
                                                  const float* __restrict__ w,
                                                  float* __restrict__ q,
                                                  float* __restrict__ k,
                                                  float* __restrict__ v) {
  __shared__ float As[64][65];  // [s][c], pad for conflict-free write
  __shared__ float Bs[64][68];  // [c][ch], pad 68 so float4 reads stay 16B-aligned
  const int ctile = blockIdx.x % 6;
  const int stile = blockIdx.x / 6;  // over B*S/64 = 128
  const int tid = threadIdx.x;
  const int row0 = stile * 64;       // fused (b,s) row base

  for (int idx = tid; idx < 64 * 64; idx += 256) {
    int s = idx >> 6, c = idx & 63;
    As[s][c] = in[(size_t)(row0 + s) * 64 + c];
  }
  for (int idx = tid; idx < 64 * 64; idx += 256) {
    int c = idx >> 6, ch = idx & 63;
    Bs[c][ch] = w[(size_t)c * 384 + ctile * 64 + ch];
  }
  __syncthreads();

  const int ts = tid >> 4, tc = tid & 15;  // 4 s-rows x 4 channels per thread
  float acc[4][4] = {};
  for (int c = 0; c < 64; ++c) {
    float av[4];
#pragma unroll
    for (int a = 0; a < 4; ++a) av[a] = As[ts * 4 + a][c];
    const float4 bv4 = *(const float4*)&Bs[c][tc * 4];
    const float bv[4] = {bv4.x, bv4.y, bv4.z, bv4.w};
#pragma unroll
    for (int a = 0; a < 4; ++a)
#pragma unroll
      for (int cc = 0; cc < 4; ++cc) acc[a][cc] = fmaf(av[a], bv[cc], acc[a][cc]);
  }

  const int b = row0 >> 12;                 // /4096
  const int sl = (row0 & 4095) + ts * 4;    // local seq pos
#pragma unroll
  for (int cc = 0; cc < 4; ++cc) {
    const int chg = ctile * 64 + tc * 4 + cc;   // 0..383
    const int sel = chg >> 7;                    // 0=q 1=k 2=v
    const int rem = chg & 127;                   // h*32+d
    float* dst = sel == 0 ? q : (sel == 1 ? k : v);
    const float4 st = make_float4(acc[0][cc], acc[1][cc], acc[2][cc], acc[3][cc]);
    *(float4*)&dst[(size_t)((b * 4 + (rem >> 5)) * 32 + (rem & 31)) * 4096 + sl] = st;
  }
}

// ---------------------------------------------------------------------------
// Kernel 2: standardize q and k per (b,h,d) row over s=4096. grid 512 blocks.
__global__ __launch_bounds__(256) void std_kernel(float* __restrict__ q,
                                                  float* __restrict__ k) {
  const int row = blockIdx.x;  // 0..255 -> q rows, 256..511 -> k rows
  float* p = (row < 256 ? q : k) + (size_t)(row & 255) * 4096;
  const int tid = threadIdx.x;
  float4 x[4];
  float sum = 0.f, sq = 0.f;
#pragma unroll
  for (int c = 0; c < 4; ++c) {
    x[c] = *(const float4*)&p[c * 1024 + tid * 4];
    sum += x[c].x + x[c].y + x[c].z + x[c].w;
    sq += x[c].x * x[c].x + x[c].y * x[c].y + x[c].z * x[c].z + x[c].w * x[c].w;
  }
#pragma unroll
  for (int off = 32; off >= 1; off >>= 1) {
    sum += __shfl_xor(sum, off, 64);
    sq += __shfl_xor(sq, off, 64);
  }
  __shared__ float red[2][4];
  if ((tid & 63) == 0) { red[0][tid >> 6] = sum; red[1][tid >> 6] = sq; }
  __syncthreads();
  const float tsum = red[0][0] + red[0][1] + red[0][2] + red[0][3];
  const float tsq = red[1][0] + red[1][1] + red[1][2] + red[1][3];
  const float mean = tsum * (1.f / 4096.f);
  const float inv = rsqrtf(tsq * (1.f / 4096.f) - mean * mean + 1e-5f);
#pragma unroll
  for (int c = 0; c < 4; ++c) {
    float4 y;
    y.x = (x[c].x - mean) * inv;
    y.y = (x[c].y - mean) * inv;
    y.z = (x[c].z - mean) * inv;
    y.w = (x[c].w - mean) * inv;
    *(float4*)&p[c * 1024 + tid * 4] = y;
  }
}

// ---------------------------------------------------------------------------
// Kernel 3: flash attention. grid = 8 (b,h) * 64 i-tiles = 512 blocks, 256 thr.
// TI=TJ=64. Thread (ti=tid/16, tj=tid%16): QK computes s[4i][4j]; PV computes
// o[4i][2d]. Rows ti*4..ti*4+3 are owned entirely within one wave -> shuffle
// row reductions, no cross-wave softmax races.
__global__ __launch_bounds__(256) void attn_kernel(const float* __restrict__ q,
                                                   const float* __restrict__ k,
                                                   const float* __restrict__ v,
                                                   float* __restrict__ o) {
  __shared__ float qs[32][68];   // [d][i]
  __shared__ float ks[32][68];   // [d][j]
  __shared__ float vs[64][34];   // [j][d]
  __shared__ float ps[64][68];   // p^T: [j][i]
  __shared__ float mrow[64], lrow[64], arow[64];

  const int itile = blockIdx.x & 63;
  const int bh = blockIdx.x >> 6;  // b*4+h
  const int i0 = itile * 64;
  const float* qb = q + (size_t)bh * 32 * 4096;
  const float* kb = k + (size_t)bh * 32 * 4096;
  const float* vb = v + (size_t)bh * 32 * 4096;
  const int tid = threadIdx.x;

  for (int idx = tid; idx < 32 * 64; idx += 256) {
    int d = idx >> 6, i = idx & 63;
    qs[d][i] = qb[(size_t)d * 4096 + i0 + i];
  }
  if (tid < 64) { mrow[tid] = -INFINITY; lrow[tid] = 0.f; }
  const int ti = tid >> 4, tj = tid & 15;
  float oacc[4][2] = {};
  __syncthreads();

  for (int j0 = 0; j0 < 4096; j0 += 64) {
    for (int idx = tid; idx < 32 * 64; idx += 256) {
      int d = idx >> 6, j = idx & 63;
      ks[d][j] = kb[(size_t)d * 4096 + j0 + j];
      vs[j][d] = vb[(size_t)d * 4096 + j0 + j];
    }
    __syncthreads();

    // --- QK^T tile (64x64), 4x4 per thread
    float sc[4][4] = {};
    for (int d = 0; d < 32; ++d) {
      const float4 qa = *(const float4*)&qs[d][ti * 4];
      const float4 ka = *(const float4*)&ks[d][tj * 4];
      const float qv[4] = {qa.x, qa.y, qa.z, qa.w};
      const float kv[4] = {ka.x, ka.y, ka.z, ka.w};
#pragma unroll
      for (int a = 0; a < 4; ++a)
#pragma unroll
        for (int jb = 0; jb < 4; ++jb) sc[a][jb] = fmaf(qv[a], kv[jb], sc[a][jb]);
    }
#pragma unroll
    for (int a = 0; a < 4; ++a)
#pragma unroll
      for (int jb = 0; jb < 4; ++jb) sc[a][jb] *= SCALE_F;

    // --- online softmax per row (16 row-mates are in the same wave)
#pragma unroll
    for (int a = 0; a < 4; ++a) {
      float rm = fmaxf(fmaxf(sc[a][0], sc[a][1]), fmaxf(sc[a][2], sc[a][3]));
#pragma unroll
      for (int off = 8; off >= 1; off >>= 1) rm = fmaxf(rm, __shfl_xor(rm, off, 16));
      const int r = ti * 4 + a;
      const float mo = mrow[r];  // all 16 lanes read before tj==0 writes (lockstep)
      const float mn = fmaxf(mo, rm);
      float rsum = 0.f;
#pragma unroll
      for (int jb = 0; jb < 4; ++jb) {
        const float pv = __expf(sc[a][jb] - mn);
        sc[a][jb] = pv;
        rsum += pv;
      }
#pragma unroll
      for (int off = 8; off >= 1; off >>= 1) rsum += __shfl_xor(rsum, off, 16);
      if (tj == 0) {
        const float al = __expf(mo - mn);  // -inf - finite -> 0 on first tile
        arow[r] = al;
        mrow[r] = mn;
        lrow[r] = lrow[r] * al + rsum;
      }
    }
    // write p^T to LDS for the PV pass
#pragma unroll
    for (int jb = 0; jb < 4; ++jb) {
      const float4 st = make_float4(sc[0][jb], sc[1][jb], sc[2][jb], sc[3][jb]);
      *(float4*)&ps[tj * 4 + jb][ti * 4] = st;
    }
    __syncthreads();

    // --- PV: o[4i][2d] += p^T . v ; rescale by alpha first
#pragma unroll
    for (int a = 0; a < 4; ++a) {
      const float al = arow[ti * 4 + a];
      oacc[a][0] *= al;
      oacc[a][1] *= al;
    }
    for (int j = 0; j < 64; ++j) {
      const float4 pv = *(const float4*)&ps[j][ti * 4];
      const float2 vv = *(const float2*)&vs[j][tj * 2];
      oacc[0][0] = fmaf(pv.x, vv.x, oacc[0][0]);
      oacc[0][1] = fmaf(pv.x, vv.y, oacc[0][1]);
      oacc[1][0] = fmaf(pv.y, vv.x, oacc[1][0]);
      oacc[1][1] = fmaf(pv.y, vv.y, oacc[1][1]);
      oacc[2][0] = fmaf(pv.z, vv.x, oacc[2][0]);
      oacc[2][1] = fmaf(pv.z, vv.y, oacc[2][1]);
      oacc[3][0] = fmaf(pv.w, vv.x, oacc[3][0]);
      oacc[3][1] = fmaf(pv.w, vv.y, oacc[3][1]);
    }
    __syncthreads();  // protect ks/vs/ps before next tile's loads
  }

  // epilogue: divide by l, write o in [b][s][h*32+d] layout
  const int b = bh >> 2, h = bh & 3;
#pragma unroll
  for (int a = 0; a < 4; ++a) {
    const int r = ti * 4 + a;
    const float invl = 1.f / lrow[r];
    const float2 st = make_float2(oacc[a][0] * invl, oacc[a][1] * invl);
    *(float2*)&o[(size_t)((b * 4096 + i0 + r) * 128) + h * 32 + tj * 2] = st;
  }
}

// ---------------------------------------------------------------------------
// Kernel 4: out = o @ w_out + b_out.  [8192,128]x[128,64]. grid 1024 blocks.
__global__ __launch_bounds__(256) void proj_kernel(const float* __restrict__ o,
                                                   const float* __restrict__ w,
                                                   const float* __restrict__ bias,
                                                   float* __restrict__ out) {
  const int tid = threadIdx.x;
  const int col = tid & 63;
  const int r = blockIdx.x * 8 + ((tid >> 6) << 1);  // 2 rows per thread
  const float* r0 = o + (size_t)r * 128;
  const float* r1 = r0 + 128;
  float a0 = bias[col], a1 = a0;
  for (int c = 0; c < 128; c += 4) {
    const float4 x0 = *(const float4*)&r0[c];
    const float4 x1 = *(const float4*)&r1[c];
    const float w0 = w[(size_t)c * 64 + col];
    const float w1 = w[(size_t)(c + 1) * 64 + col];
    const float w2 = w[(size_t)(c + 2) * 64 + col];
    const float w3 = w[(size_t)(c + 3) * 64 + col];
    a0 = fmaf(x0.x, w0, a0); a0 = fmaf(x0.y, w1, a0);
    a0 = fmaf(x0.z, w2, a0); a0 = fmaf(x0.w, w3, a0);
    a1 = fmaf(x1.x, w0, a1); a1 = fmaf(x1.y, w1, a1);
    a1 = fmaf(x1.z, w2, a1); a1 = fmaf(x1.w, w3, a1);
  }
  out[(size_t)r * 64 + col] = a0;
  out[(size_t)(r + 1) * 64 + col] = a1;
}

// ---------------------------------------------------------------------------
extern "C" void kernel_launch(void* const* d_in, const int* in_sizes, int n_in,
                              void* d_out, int out_size, void* d_ws, size_t ws_size,
                              hipStream_t stream) {
  const float* input = (const float*)d_in[0];  // [2,16,16,16,64]
  const float* w_qkv = (const float*)d_in[1];  // [64,384]
  const float* w_out = (const float*)d_in[2];  // [128,64]
  const float* b_out = (const float*)d_in[3];  // [64]
  float* W = (float*)d_ws;                     // need 16 MB
  float* q = W;
  float* k = W + (1u << 20);
  float* v = W + (2u << 20);
  float* ob = W + (3u << 20);
  float* out = (float*)d_out;

  hipLaunchKernelGGL(qkv_kernel, dim3(768), dim3(256), 0, stream, input, w_qkv, q, k, v);
  hipLaunchKernelGGL(std_kernel, dim3(512), dim3(256), 0, stream, q, k);
  hipLaunchKernelGGL(attn_kernel, dim3(512), dim3(256), 0, stream, q, k, v, ob);
  hipLaunchKernelGGL(proj_kernel, dim3(1024), dim3(256), 0, stream, ob, w_out, b_out, out);
}

// Round 2
// 297.977 us; speedup vs baseline: 3.0162x; 3.0162x over previous
//
#include <hip/hip_runtime.h>
#include <math.h>

// B=2, S=4096, H=4, D=32, C=64, HID=128. SCALE=16 folded as 16*log2(e) into q.
// ws layout (bytes):
//   0        : qf fp32 [8][4096][32]  -> packed in-place to uint32 (hi<<16|lo)
//   4 MB     : kf fp32 [8][4096][32]  -> packed in-place
//   8 MB     : vpack uint32 [8][32][4096] (written packed by qkv kernel)
//   12 MB    : o bf16 [8192][128]
//   14 MB    : stats fp32: sum[512], sumsq[512]   (row = tensor*256 + bh*32 + d)
// total 14 MB + 4 KB

typedef __attribute__((ext_vector_type(8))) short short8;
typedef __attribute__((ext_vector_type(4))) float f32x4;

#define QSCALE 23.083120654223414f /* 16 * log2(e) */

__device__ inline uint32_t pack_hilo(float y) {
  uint32_t uy = __float_as_uint(y);
  uint32_t hb = (uy + 0x7fffu + ((uy >> 16) & 1u)) >> 16;  // RNE bf16
  float hf = __uint_as_float(hb << 16);
  float r = y - hf;
  uint32_t ur = __float_as_uint(r);
  uint32_t lb = (ur + 0x7fffu + ((ur >> 16) & 1u)) >> 16;
  return (hb << 16) | (lb & 0xffffu);
}

__device__ inline ushort f32_to_bf16(float y) {
  uint32_t uy = __float_as_uint(y);
  return (ushort)((uy + 0x7fffu + ((uy >> 16) & 1u)) >> 16);
}

// ---------------------------------------------------------------------------
// Kernel 1: qkv = input @ w_qkv. q,k -> fp32 [bh][s][32]; v -> packed hi/lo
// bf16 uint32 [bh][32][4096]. Also accumulates per-(tensor,bh,d) sum/sumsq.
// grid 768 = 128 s-tiles * 6 ch-tiles, 256 threads.
__global__ __launch_bounds__(256) void qkv_kernel(const float* __restrict__ in,
                                                  const float* __restrict__ w,
                                                  float* __restrict__ qf,
                                                  float* __restrict__ kf,
                                                  uint32_t* __restrict__ vpack,
                                                  float* __restrict__ ssumg,
                                                  float* __restrict__ ssqg) {
  __shared__ float As[64][65];
  __shared__ float Bs[64][68];
  __shared__ float ssum[64], ssq[64];
  const int ctile = blockIdx.x % 6;
  const int stile = blockIdx.x / 6;
  const int tid = threadIdx.x;
  const int row0 = stile * 64;
  const int sel = ctile >> 1;  // 0=q 1=k 2=v

  if (tid < 64) { ssum[tid] = 0.f; ssq[tid] = 0.f; }
  for (int idx = tid; idx < 64 * 64; idx += 256) {
    int s = idx >> 6, c = idx & 63;
    As[s][c] = in[(size_t)(row0 + s) * 64 + c];
  }
  for (int idx = tid; idx < 64 * 64; idx += 256) {
    int c = idx >> 6, ch = idx & 63;
    Bs[c][ch] = w[(size_t)c * 384 + ctile * 64 + ch];
  }
  __syncthreads();

  const int ts = tid >> 4, tc = tid & 15;
  float acc[4][4] = {};
  for (int c = 0; c < 64; ++c) {
    float av[4];
#pragma unroll
    for (int a = 0; a < 4; ++a) av[a] = As[ts * 4 + a][c];
    const float4 bv4 = *(const float4*)&Bs[c][tc * 4];
    const float bv[4] = {bv4.x, bv4.y, bv4.z, bv4.w};
#pragma unroll
    for (int a = 0; a < 4; ++a)
#pragma unroll
      for (int cc = 0; cc < 4; ++cc) acc[a][cc] = fmaf(av[a], bv[cc], acc[a][cc]);
  }

  const int b = row0 >> 12;
  const int sl = (row0 & 4095) + ts * 4;
  const int chg0 = ctile * 64 + tc * 4;  // first of 4 consecutive channels

  if (sel < 2) {
    // q or k: fp32 [bh][s][32] writes, float4 along d
    const int hd0 = chg0 & 127;
    const int h = hd0 >> 5, d0 = hd0 & 31;
    float* dst = (sel == 0 ? qf : kf) + ((size_t)(b * 4 + h) * 4096) * 32 + d0;
#pragma unroll
    for (int a = 0; a < 4; ++a) {
      float4 st = make_float4(acc[a][0], acc[a][1], acc[a][2], acc[a][3]);
      *(float4*)&dst[(size_t)(sl + a) * 32] = st;
    }
    // stats: per-channel partial sums over this block's 64 s values
#pragma unroll
    for (int cc = 0; cc < 4; ++cc) {
      float sm = acc[0][cc] + acc[1][cc] + acc[2][cc] + acc[3][cc];
      float sq = acc[0][cc] * acc[0][cc] + acc[1][cc] * acc[1][cc] +
                 acc[2][cc] * acc[2][cc] + acc[3][cc] * acc[3][cc];
      atomicAdd(&ssum[tc * 4 + cc], sm);
      atomicAdd(&ssq[tc * 4 + cc], sq);
    }
    __syncthreads();
    if (tid < 64) {
      const int chg = ctile * 64 + tid;
      const int gidx = sel * 256 + b * 128 + (chg & 127);
      atomicAdd(&ssumg[gidx], ssum[tid]);
      atomicAdd(&ssqg[gidx], ssq[tid]);
    }
  } else {
    // v: packed hi/lo bf16 [bh][d][s], uint4 along s
#pragma unroll
    for (int cc = 0; cc < 4; ++cc) {
      const int hd = (chg0 + cc) & 127;
      const int h = hd >> 5, d = hd & 31;
      uint4 st;
      st.x = pack_hilo(acc[0][cc]);
      st.y = pack_hilo(acc[1][cc]);
      st.z = pack_hilo(acc[2][cc]);
      st.w = pack_hilo(acc[3][cc]);
      *(uint4*)&vpack[((size_t)(b * 4 + h) * 32 + d) * 4096 + sl] = st;
    }
  }
}

// ---------------------------------------------------------------------------
// Kernel 2: finalize stats, standardize q/k, fold QSCALE into q, pack hi/lo
// bf16 into the same buffer (in place). grid 256 = 2 tensors * 8 bh * 16 chunks.
__global__ __launch_bounds__(256) void norm_kernel(float* __restrict__ qf,
                                                   float* __restrict__ kf,
                                                   const float* __restrict__ ssumg,
                                                   const float* __restrict__ ssqg) {
  const int bx = blockIdx.x;
  const int tensor = bx >> 7;
  const int rem = bx & 127;
  const int bh = rem >> 4;
  const int s0 = (rem & 15) * 256;
  const int tid = threadIdx.x;
  float* src = (tensor ? kf : qf) + ((size_t)bh * 4096 + s0) * 32;
  const float scale = tensor ? 1.0f : QSCALE;
  const int d0 = (tid & 7) * 4;
  const int sbase = tensor * 256 + bh * 32 + d0;
  float mean[4], inv[4];
#pragma unroll
  for (int e = 0; e < 4; ++e) {
    float mu = ssumg[sbase + e] * (1.f / 4096.f);
    float var = ssqg[sbase + e] * (1.f / 4096.f) - mu * mu;
    mean[e] = mu;
    inv[e] = rsqrtf(var + 1e-5f) * scale;
  }
#pragma unroll
  for (int i = 0; i < 8; ++i) {
    const int id = tid + i * 256;
    const int s = id >> 3;
    float* p = &src[(size_t)s * 32 + d0];
    float4 x = *(const float4*)p;
    uint4 st;
    st.x = pack_hilo((x.x - mean[0]) * inv[0]);
    st.y = pack_hilo((x.y - mean[1]) * inv[1]);
    st.z = pack_hilo((x.z - mean[2]) * inv[2]);
    st.w = pack_hilo((x.w - mean[3]) * inv[3]);
    *(uint4*)p = st;
  }
}

// ---------------------------------------------------------------------------
// Kernel 3: flash attention with bf16 MFMA (16x16x32), split-precision QK.
// grid 512 = 8 bh * 64 i-tiles, 256 threads (4 waves). Wave w owns i-rows
// [i0+w*16, i0+w*16+16).
__global__ __launch_bounds__(256) void attn_kernel(const uint32_t* __restrict__ qp,
                                                   const uint32_t* __restrict__ kp,
                                                   const uint32_t* __restrict__ vp,
                                                   ushort* __restrict__ o) {
  __shared__ ushort ks_hi[64][40], ks_lo[64][40];  // [j][d], rows 80B (16B-aligned)
  __shared__ ushort vs_hi[32][72], vs_lo[32][72];  // [d][j], rows 144B
  __shared__ ushort ps[64][72];                    // P bf16 [i][j]

  const int tid = threadIdx.x;
  const int bh = blockIdx.x >> 6;
  const int i0 = (blockIdx.x & 63) * 64;
  const int w = tid >> 6, lane = tid & 63, quad = lane >> 4, tl = lane & 15;

  // q A-frags: A[m=tl -> i][k=quad*8+j -> d], hi and lo
  const uint32_t* qrow = qp + ((size_t)bh * 4096 + i0 + w * 16 + tl) * 32 + quad * 8;
  uint4 qa = *(const uint4*)qrow;
  uint4 qb = *(const uint4*)(qrow + 4);
  short8 qhi, qlo;
  {
    uint32_t u[8] = {qa.x, qa.y, qa.z, qa.w, qb.x, qb.y, qb.z, qb.w};
#pragma unroll
    for (int j = 0; j < 8; ++j) { qhi[j] = (short)(u[j] >> 16); qlo[j] = (short)(u[j] & 0xffff); }
  }

  const uint32_t* kbase = kp + (size_t)bh * 4096 * 32;
  const uint32_t* vbase = vp + (size_t)bh * 32 * 4096;

  f32x4 oacc[2] = {{0.f, 0.f, 0.f, 0.f}, {0.f, 0.f, 0.f, 0.f}};
  float m[4] = {-INFINITY, -INFINITY, -INFINITY, -INFINITY};
  float l[4] = {0.f, 0.f, 0.f, 0.f};

  for (int j0 = 0; j0 < 4096; j0 += 64) {
    __syncthreads();  // protect ks/vs from previous iteration's readers
#pragma unroll
    for (int it = 0; it < 2; ++it) {
      const int c = tid + it * 256;
      {  // k tile: [64 j][32 d] packed -> hi/lo
        const int row = c >> 3, ch = c & 7;
        uint4 t4 = *(const uint4*)&kbase[(size_t)(j0 + row) * 32 + ch * 4];
        ushort4 h4 = {(ushort)(t4.x >> 16), (ushort)(t4.y >> 16), (ushort)(t4.z >> 16), (ushort)(t4.w >> 16)};
        ushort4 l4 = {(ushort)t4.x, (ushort)t4.y, (ushort)t4.z, (ushort)t4.w};
        *(ushort4*)&ks_hi[row][ch * 4] = h4;
        *(ushort4*)&ks_lo[row][ch * 4] = l4;
      }
      {  // v tile: [32 d][64 j] packed -> hi/lo
        const int row = c >> 4, ch = c & 15;
        uint4 t4 = *(const uint4*)&vbase[(size_t)row * 4096 + j0 + ch * 4];
        ushort4 h4 = {(ushort)(t4.x >> 16), (ushort)(t4.y >> 16), (ushort)(t4.z >> 16), (ushort)(t4.w >> 16)};
        ushort4 l4 = {(ushort)t4.x, (ushort)t4.y, (ushort)t4.z, (ushort)t4.w};
        *(ushort4*)&vs_hi[row][ch * 4] = h4;
        *(ushort4*)&vs_lo[row][ch * 4] = l4;
      }
    }
    __syncthreads();

    // --- QK^T: sim[i][j], split hi/lo (3 MFMAs per 16x16 tile)
    f32x4 sc[4];
#pragma unroll
    for (int jt = 0; jt < 4; ++jt) {
      short8 kh = *(const short8*)&ks_hi[jt * 16 + tl][quad * 8];
      short8 kl = *(const short8*)&ks_lo[jt * 16 + tl][quad * 8];
      f32x4 z = {0.f, 0.f, 0.f, 0.f};
      z = __builtin_amdgcn_mfma_f32_16x16x32_bf16(qhi, kh, z, 0, 0, 0);
      z = __builtin_amdgcn_mfma_f32_16x16x32_bf16(qhi, kl, z, 0, 0, 0);
      z = __builtin_amdgcn_mfma_f32_16x16x32_bf16(qlo, kh, z, 0, 0, 0);
      sc[jt] = z;
    }

    // --- online softmax (base-2; scale folded into q). Row r = quad*4+reg.
#pragma unroll
    for (int r = 0; r < 4; ++r) {
      float mx = fmaxf(fmaxf(sc[0][r], sc[1][r]), fmaxf(sc[2][r], sc[3][r]));
      mx = fmaxf(mx, __shfl_xor(mx, 1));
      mx = fmaxf(mx, __shfl_xor(mx, 2));
      mx = fmaxf(mx, __shfl_xor(mx, 4));
      mx = fmaxf(mx, __shfl_xor(mx, 8));
      const float mn = fmaxf(m[r], mx);
      const float a = exp2f(m[r] - mn);
      float rs = 0.f;
#pragma unroll
      for (int jt = 0; jt < 4; ++jt) {
        float pv = exp2f(sc[jt][r] - mn);
        sc[jt][r] = pv;
        rs += pv;
      }
      rs += __shfl_xor(rs, 1);
      rs += __shfl_xor(rs, 2);
      rs += __shfl_xor(rs, 4);
      rs += __shfl_xor(rs, 8);
      m[r] = mn;
      l[r] = l[r] * a + rs;
      oacc[0][r] *= a;
      oacc[1][r] *= a;
    }

    // --- P (C-layout) -> LDS [i][j] bf16
#pragma unroll
    for (int r = 0; r < 4; ++r)
#pragma unroll
      for (int jt = 0; jt < 4; ++jt)
        ps[w * 16 + quad * 4 + r][jt * 16 + tl] = f32_to_bf16(sc[jt][r]);

    // --- PV: O[i][d] += P . V  (A = P from LDS, B = V hi/lo)
    short8 pa0 = *(const short8*)&ps[w * 16 + tl][quad * 8];
    short8 pa1 = *(const short8*)&ps[w * 16 + tl][32 + quad * 8];
#pragma unroll
    for (int dt = 0; dt < 2; ++dt) {
      short8 vh0 = *(const short8*)&vs_hi[dt * 16 + tl][quad * 8];
      short8 vh1 = *(const short8*)&vs_hi[dt * 16 + tl][32 + quad * 8];
      short8 vl0 = *(const short8*)&vs_lo[dt * 16 + tl][quad * 8];
      short8 vl1 = *(const short8*)&vs_lo[dt * 16 + tl][32 + quad * 8];
      f32x4 z = oacc[dt];
      z = __builtin_amdgcn_mfma_f32_16x16x32_bf16(pa0, vh0, z, 0, 0, 0);
      z = __builtin_amdgcn_mfma_f32_16x16x32_bf16(pa1, vh1, z, 0, 0, 0);
      z = __builtin_amdgcn_mfma_f32_16x16x32_bf16(pa0, vl0, z, 0, 0, 0);
      z = __builtin_amdgcn_mfma_f32_16x16x32_bf16(pa1, vl1, z, 0, 0, 0);
      oacc[dt] = z;
    }
  }

  // epilogue: divide by l, write o bf16 [b][s][h*32+d]
  const int b = bh >> 2, h = bh & 3;
#pragma unroll
  for (int r = 0; r < 4; ++r) {
    const float invl = 1.f / l[r];
    const int i = i0 + w * 16 + quad * 4 + r;
#pragma unroll
    for (int dt = 0; dt < 2; ++dt) {
      float y = oacc[dt][r] * invl;
      o[((size_t)(b * 4096 + i)) * 128 + h * 32 + dt * 16 + tl] = f32_to_bf16(y);
    }
  }
}

// ---------------------------------------------------------------------------
// Kernel 4: out = o(bf16) @ w_out + b_out. [8192,128]x[128,64]. 1024 blocks.
__global__ __launch_bounds__(256) void proj_kernel(const ushort* __restrict__ o,
                                                   const float* __restrict__ w,
                                                   const float* __restrict__ bias,
                                                   float* __restrict__ out) {
  const int tid = threadIdx.x;
  const int col = tid & 63;
  const int r = blockIdx.x * 8 + ((tid >> 6) << 1);
  const ushort* r0 = o + (size_t)r * 128;
  const ushort* r1 = r0 + 128;
  float a0 = bias[col], a1 = a0;
  for (int c = 0; c < 128; c += 4) {
    ushort4 x0 = *(const ushort4*)&r0[c];
    ushort4 x1 = *(const ushort4*)&r1[c];
    const float w0 = w[(size_t)c * 64 + col];
    const float w1 = w[(size_t)(c + 1) * 64 + col];
    const float w2 = w[(size_t)(c + 2) * 64 + col];
    const float w3 = w[(size_t)(c + 3) * 64 + col];
    a0 = fmaf(__uint_as_float((uint32_t)x0.x << 16), w0, a0);
    a0 = fmaf(__uint_as_float((uint32_t)x0.y << 16), w1, a0);
    a0 = fmaf(__uint_as_float((uint32_t)x0.z << 16), w2, a0);
    a0 = fmaf(__uint_as_float((uint32_t)x0.w << 16), w3, a0);
    a1 = fmaf(__uint_as_float((uint32_t)x1.x << 16), w0, a1);
    a1 = fmaf(__uint_as_float((uint32_t)x1.y << 16), w1, a1);
    a1 = fmaf(__uint_as_float((uint32_t)x1.z << 16), w2, a1);
    a1 = fmaf(__uint_as_float((uint32_t)x1.w << 16), w3, a1);
  }
  out[(size_t)r * 64 + col] = a0;
  out[(size_t)(r + 1) * 64 + col] = a1;
}

// ---------------------------------------------------------------------------
extern "C" void kernel_launch(void* const* d_in, const int* in_sizes, int n_in,
                              void* d_out, int out_size, void* d_ws, size_t ws_size,
                              hipStream_t stream) {
  const float* input = (const float*)d_in[0];
  const float* w_qkv = (const float*)d_in[1];
  const float* w_out = (const float*)d_in[2];
  const float* b_out = (const float*)d_in[3];

  char* W = (char*)d_ws;
  float* qf = (float*)(W + 0);
  float* kf = (float*)(W + (4u << 20));
  uint32_t* vpack = (uint32_t*)(W + (8u << 20));
  ushort* obf = (ushort*)(W + (12u << 20));
  float* stats = (float*)(W + (14u << 20));
  float* ssumg = stats;
  float* ssqg = stats + 512;
  float* out = (float*)d_out;

  hipMemsetAsync(stats, 0, 1024 * sizeof(float), stream);
  hipLaunchKernelGGL(qkv_kernel, dim3(768), dim3(256), 0, stream, input, w_qkv, qf, kf,
                     vpack, ssumg, ssqg);
  hipLaunchKernelGGL(norm_kernel, dim3(256), dim3(256), 0, stream, qf, kf, ssumg, ssqg);
  hipLaunchKernelGGL(attn_kernel, dim3(512), dim3(256), 0, stream, (const uint32_t*)qf,
                     (const uint32_t*)kf, vpack, obf);
  hipLaunchKernelGGL(proj_kernel, dim3(1024), dim3(256), 0, stream, obf, w_out, b_out, out);
}

// Round 3
// 174.257 us; speedup vs baseline: 5.1576x; 1.7100x over previous
//
#include <hip/hip_runtime.h>
#include <math.h>
#include <stdint.h>

// B=2, S=4096, H=4, D=32, C=64. SCALE=16 folded as 16*log2(e) into q (base-2 softmax).
//
// ws layout (bytes), total 14 MB + 4 KB (same footprint R2 proved safe):
//   0    : qf fp32 [8][4096][32]  -> packed uint32 (hi<<16|lo) in place by norm
//   4 MB : kf fp32 [8][4096][32]  -> dead after norm; REUSED as o fp32 [8192][128]
//   8 MB : k_hi ushort [8][4096][32]
//   10 MB: k_lo ushort [8][4096][32]
//   12 MB: v_hi ushort [8][32][4096]
//   14 MB: stats fp32 sum[512], sumsq[512]

typedef __attribute__((ext_vector_type(8))) short short8;
typedef __attribute__((ext_vector_type(4))) float f32x4;

#define QSCALE 23.083120654223414f /* 16 * log2(e) */

__device__ inline uint32_t pack_hilo(float y) {
  uint32_t uy = __float_as_uint(y);
  uint32_t hb = (uy + 0x7fffu + ((uy >> 16) & 1u)) >> 16;  // RNE bf16
  float hf = __uint_as_float(hb << 16);
  float r = y - hf;
  uint32_t ur = __float_as_uint(r);
  uint32_t lb = (ur + 0x7fffu + ((ur >> 16) & 1u)) >> 16;
  return (hb << 16) | (lb & 0xffffu);
}

__device__ inline ushort f32_to_bf16(float y) {
  uint32_t uy = __float_as_uint(y);
  return (ushort)((uy + 0x7fffu + ((uy >> 16) & 1u)) >> 16);
}

// ---------------------------------------------------------------------------
// Kernel 1: qkv = input @ w_qkv. q,k -> fp32 [bh][s][32]; v -> bf16-hi ushort
// [bh][32][4096]. Accumulates per-(tensor,bh,d) sum/sumsq for q,k.
__global__ __launch_bounds__(256) void qkv_kernel(const float* __restrict__ in,
                                                  const float* __restrict__ w,
                                                  float* __restrict__ qf,
                                                  float* __restrict__ kf,
                                                  ushort* __restrict__ vhg,
                                                  float* __restrict__ ssumg,
                                                  float* __restrict__ ssqg) {
  __shared__ float As[64][65];
  __shared__ float Bs[64][68];
  __shared__ float ssum[64], ssq[64];
  const int ctile = blockIdx.x % 6;
  const int stile = blockIdx.x / 6;
  const int tid = threadIdx.x;
  const int row0 = stile * 64;
  const int sel = ctile >> 1;  // 0=q 1=k 2=v

  if (tid < 64) { ssum[tid] = 0.f; ssq[tid] = 0.f; }
  for (int idx = tid; idx < 64 * 64; idx += 256) {
    int s = idx >> 6, c = idx & 63;
    As[s][c] = in[(size_t)(row0 + s) * 64 + c];
  }
  for (int idx = tid; idx < 64 * 64; idx += 256) {
    int c = idx >> 6, ch = idx & 63;
    Bs[c][ch] = w[(size_t)c * 384 + ctile * 64 + ch];
  }
  __syncthreads();

  const int ts = tid >> 4, tc = tid & 15;
  float acc[4][4] = {};
  for (int c = 0; c < 64; ++c) {
    float av[4];
#pragma unroll
    for (int a = 0; a < 4; ++a) av[a] = As[ts * 4 + a][c];
    const float4 bv4 = *(const float4*)&Bs[c][tc * 4];
    const float bv[4] = {bv4.x, bv4.y, bv4.z, bv4.w};
#pragma unroll
    for (int a = 0; a < 4; ++a)
#pragma unroll
      for (int cc = 0; cc < 4; ++cc) acc[a][cc] = fmaf(av[a], bv[cc], acc[a][cc]);
  }

  const int b = row0 >> 12;
  const int sl = (row0 & 4095) + ts * 4;
  const int chg0 = ctile * 64 + tc * 4;

  if (sel < 2) {
    const int hd0 = chg0 & 127;
    const int h = hd0 >> 5, d0 = hd0 & 31;
    float* dst = (sel == 0 ? qf : kf) + ((size_t)(b * 4 + h) * 4096) * 32 + d0;
#pragma unroll
    for (int a = 0; a < 4; ++a) {
      float4 st = make_float4(acc[a][0], acc[a][1], acc[a][2], acc[a][3]);
      *(float4*)&dst[(size_t)(sl + a) * 32] = st;
    }
#pragma unroll
    for (int cc = 0; cc < 4; ++cc) {
      float sm = acc[0][cc] + acc[1][cc] + acc[2][cc] + acc[3][cc];
      float sq = acc[0][cc] * acc[0][cc] + acc[1][cc] * acc[1][cc] +
                 acc[2][cc] * acc[2][cc] + acc[3][cc] * acc[3][cc];
      atomicAdd(&ssum[tc * 4 + cc], sm);
      atomicAdd(&ssq[tc * 4 + cc], sq);
    }
    __syncthreads();
    if (tid < 64) {
      const int chg = ctile * 64 + tid;
      const int gidx = sel * 256 + b * 128 + (chg & 127);
      atomicAdd(&ssumg[gidx], ssum[tid]);
      atomicAdd(&ssqg[gidx], ssq[tid]);
    }
  } else {
    // v: bf16 hi only, [bh][d][s]
#pragma unroll
    for (int cc = 0; cc < 4; ++cc) {
      const int hd = (chg0 + cc) & 127;
      const int h = hd >> 5, d = hd & 31;
      ushort4 st;
      st.x = f32_to_bf16(acc[0][cc]);
      st.y = f32_to_bf16(acc[1][cc]);
      st.z = f32_to_bf16(acc[2][cc]);
      st.w = f32_to_bf16(acc[3][cc]);
      *(ushort4*)&vhg[((size_t)(b * 4 + h) * 32 + d) * 4096 + sl] = st;
    }
  }
}

// ---------------------------------------------------------------------------
// Kernel 2: standardize. q: fold QSCALE, pack hi/lo uint32 in place.
// k: write separate k_hi / k_lo ushort buffers. grid 256 blocks.
__global__ __launch_bounds__(256) void norm_kernel(float* __restrict__ qf,
                                                   const float* __restrict__ kf,
                                                   ushort* __restrict__ khg,
                                                   ushort* __restrict__ klg,
                                                   const float* __restrict__ ssumg,
                                                   const float* __restrict__ ssqg) {
  const int bx = blockIdx.x;
  const int tensor = bx >> 7;
  const int rem = bx & 127;
  const int bh = rem >> 4;
  const int s0 = (rem & 15) * 256;
  const int tid = threadIdx.x;
  const int d0 = (tid & 7) * 4;
  const int sbase = tensor * 256 + bh * 32 + d0;
  const float scale = tensor ? 1.0f : QSCALE;
  float mean[4], inv[4];
#pragma unroll
  for (int e = 0; e < 4; ++e) {
    float mu = ssumg[sbase + e] * (1.f / 4096.f);
    float var = ssqg[sbase + e] * (1.f / 4096.f) - mu * mu;
    mean[e] = mu;
    inv[e] = rsqrtf(var + 1e-5f) * scale;
  }
  if (tensor == 0) {
    float* src = qf + ((size_t)bh * 4096 + s0) * 32;
#pragma unroll
    for (int i = 0; i < 8; ++i) {
      const int s = (tid + i * 256) >> 3;
      float* p = &src[(size_t)s * 32 + d0];
      float4 x = *(const float4*)p;
      uint4 st;
      st.x = pack_hilo((x.x - mean[0]) * inv[0]);
      st.y = pack_hilo((x.y - mean[1]) * inv[1]);
      st.z = pack_hilo((x.z - mean[2]) * inv[2]);
      st.w = pack_hilo((x.w - mean[3]) * inv[3]);
      *(uint4*)p = st;
    }
  } else {
    const float* src = kf + ((size_t)bh * 4096 + s0) * 32;
    ushort* dh = khg + ((size_t)bh * 4096 + s0) * 32 + d0;
    ushort* dl = klg + ((size_t)bh * 4096 + s0) * 32 + d0;
#pragma unroll
    for (int i = 0; i < 8; ++i) {
      const int s = (tid + i * 256) >> 3;
      float4 x = *(const float4*)&src[(size_t)s * 32 + d0];
      float y[4] = {(x.x - mean[0]) * inv[0], (x.y - mean[1]) * inv[1],
                    (x.z - mean[2]) * inv[2], (x.w - mean[3]) * inv[3]};
      ushort4 hi, lo;
      ushort* hp = (ushort*)&hi;
      ushort* lp = (ushort*)&lo;
#pragma unroll
      for (int e = 0; e < 4; ++e) {
        ushort h = f32_to_bf16(y[e]);
        hp[e] = h;
        lp[e] = f32_to_bf16(y[e] - __uint_as_float((uint32_t)h << 16));
      }
      *(ushort4*)&dh[(size_t)s * 32] = hi;
      *(ushort4*)&dl[(size_t)s * 32] = lo;
    }
  }
}

// ---------------------------------------------------------------------------
// Kernel 3: flash attention, S^T-orientation (rows-in-lanes).
// grid 512 = 8 bh * 64 i-tiles; 768 threads = 3 j-streams * 4 waves.
// Stream s covers j-tiles [0,22)/[22,43)/[43,64); partials merged in LDS.
//
// QK^T computed as S^T = K·Q^T: C[m=j(in-tile)][n=i=tl]. K stored to LDS with a
// sigma row permutation so that each lane's 16 P values are exactly the
// in-lane B-fragment (k=j=q*8+jj) needed by PV (O^T = V^T·P^T) — no LDS
// round-trip for P. m/l are one scalar per lane (row i=tl).
#define STREAM_LDS 14848
__global__ __launch_bounds__(768, 6) void attn_kernel(const uint32_t* __restrict__ qp,
                                                      const ushort* __restrict__ khg,
                                                      const ushort* __restrict__ klg,
                                                      const ushort* __restrict__ vhg,
                                                      float* __restrict__ o) {
  __shared__ char lds[44544];  // 3 * (khi 5120 + klo 5120 + vhi 4608); merge region unions

  const int tid = threadIdx.x;
  const int strm = tid >> 8;
  const int st = tid & 255;
  const int w = st >> 6;
  const int lane = tid & 63;
  const int q = lane >> 4, tl = lane & 15;
  const int bh = blockIdx.x >> 6;
  const int i0 = (blockIdx.x & 63) * 64;

  ushort* KHI = (ushort*)(lds + strm * STREAM_LDS);  // [64][40] rows sigma-permuted
  ushort* KLO = KHI + 2560;                          // [64][40]
  ushort* VHI = KHI + 5120;                          // [32][72] = [d][j]

  // --- q B-frags: B[k=d=q*8+jj][n=i=tl], hi/lo
  const int irow = i0 + w * 16 + tl;
  const uint32_t* qptr = qp + ((size_t)bh * 4096 + irow) * 32 + q * 8;
  uint4 qa = *(const uint4*)qptr;
  uint4 qb = *(const uint4*)(qptr + 4);
  short8 qhi, qlo;
  {
    uint32_t u[8] = {qa.x, qa.y, qa.z, qa.w, qb.x, qb.y, qb.z, qb.w};
#pragma unroll
    for (int j = 0; j < 8; ++j) { qhi[j] = (short)(u[j] >> 16); qlo[j] = (short)(u[j] & 0xffff); }
  }

  // --- staging addresses (fixed per thread; only j0 advances)
  const int jr = st >> 2, ck = st & 3;  // k: 64 rows x 4 chunks of 16B
  const int sig = ((((jr >> 5) & 1) * 2 + ((jr >> 2) & 1)) << 4) +
                  ((((jr >> 3) & 3)) << 2) + (jr & 3);  // sigma row permutation
  const ushort* khsrc = khg + ((size_t)bh * 4096 + jr) * 32 + ck * 8;
  const ushort* klsrc = klg + ((size_t)bh * 4096 + jr) * 32 + ck * 8;
  ushort* khdst = &KHI[sig * 40 + ck * 8];
  ushort* kldst = &KLO[sig * 40 + ck * 8];
  const int dr = st >> 3, cv = st & 7;  // v: 32 rows x 8 chunks of 16B
  const ushort* vsrc = vhg + ((size_t)bh * 32 + dr) * 4096 + cv * 8;
  ushort* vdst = &VHI[dr * 72 + cv * 8];

  const int t0 = (strm == 0) ? 0 : (strm == 1 ? 22 : 43);
  const int t1 = (strm == 0) ? 22 : (strm == 1 ? 43 : 64);

  f32x4 oacc[2] = {{0.f, 0.f, 0.f, 0.f}, {0.f, 0.f, 0.f, 0.f}};
  float m = -INFINITY, l = 0.f;

  for (int it = 0; it < 22; ++it) {
    const int tile = t0 + it;
    const bool valid = tile < t1;  // wave-uniform (waves don't straddle streams)
    const int j0 = tile * 64;
    __syncthreads();
    if (valid) {
      *(uint4*)khdst = *(const uint4*)(khsrc + (size_t)j0 * 32);
      *(uint4*)kldst = *(const uint4*)(klsrc + (size_t)j0 * 32);
      *(uint4*)vdst = *(const uint4*)(vsrc + j0);
    }
    __syncthreads();
    if (!valid) continue;  // barriers are at loop top; counts stay matched

    // --- S^T tiles: A = K rows (sigma-permuted), B = Q frags. 3 MFMAs/tile.
    f32x4 sc[4];
#pragma unroll
    for (int jt = 0; jt < 4; ++jt) {
      short8 kh = *(const short8*)&KHI[(jt * 16 + tl) * 40 + q * 8];
      short8 kl = *(const short8*)&KLO[(jt * 16 + tl) * 40 + q * 8];
      f32x4 z = {0.f, 0.f, 0.f, 0.f};
      z = __builtin_amdgcn_mfma_f32_16x16x32_bf16(kh, qhi, z, 0, 0, 0);
      z = __builtin_amdgcn_mfma_f32_16x16x32_bf16(kh, qlo, z, 0, 0, 0);
      z = __builtin_amdgcn_mfma_f32_16x16x32_bf16(kl, qhi, z, 0, 0, 0);
      sc[jt] = z;
    }
    // lane (q,tl) now holds S[i=tl][j = 32*(jt>>1) + 8*q + 4*(jt&1) + r]

    // --- online softmax, base-2; row i=tl spread over regs + quads
    f32x4 vm;
#pragma unroll
    for (int r = 0; r < 4; ++r) vm[r] = fmaxf(fmaxf(sc[0][r], sc[1][r]), fmaxf(sc[2][r], sc[3][r]));
    float mx = fmaxf(fmaxf(vm[0], vm[1]), fmaxf(vm[2], vm[3]));
    mx = fmaxf(mx, __shfl_xor(mx, 16));
    mx = fmaxf(mx, __shfl_xor(mx, 32));
    const float mn = fmaxf(m, mx);
    const float al = exp2f(m - mn);
    m = mn;
#pragma unroll
    for (int jt = 0; jt < 4; ++jt)
#pragma unroll
      for (int r = 0; r < 4; ++r) sc[jt][r] = exp2f(sc[jt][r] - mn);
    f32x4 vs;
#pragma unroll
    for (int r = 0; r < 4; ++r) vs[r] = (sc[0][r] + sc[1][r]) + (sc[2][r] + sc[3][r]);
    float rs = (vs[0] + vs[1]) + (vs[2] + vs[3]);
    rs += __shfl_xor(rs, 16);
    rs += __shfl_xor(rs, 32);
    l = l * al + rs;
    oacc[0] *= al;
    oacc[1] *= al;

    // --- P -> bf16 pairs, fully in-lane (thanks to sigma): pb0 = j in [0,32),
    // pb1 = j in [32,64) at k=q*8+jj exactly.
    uint32_t pk[8];
#pragma unroll
    for (int jt = 0; jt < 4; ++jt)
#pragma unroll
      for (int p = 0; p < 2; ++p) {
        uint32_t u0 = __float_as_uint(sc[jt][2 * p]) + 0x8000u;
        uint32_t u1 = __float_as_uint(sc[jt][2 * p + 1]) + 0x8000u;
        pk[jt * 2 + p] = __builtin_amdgcn_perm(u1, u0, 0x07060302u);
      }
    union { uint32_t u[4]; short8 s; } c0, c1;
    c0.u[0] = pk[0]; c0.u[1] = pk[1]; c0.u[2] = pk[2]; c0.u[3] = pk[3];
    c1.u[0] = pk[4]; c1.u[1] = pk[5]; c1.u[2] = pk[6]; c1.u[3] = pk[7];

    // --- PV: O^T = V^T · P^T. A = V rows d (b128 from [d][j]), B = P frags.
#pragma unroll
    for (int dt = 0; dt < 2; ++dt) {
      short8 va0 = *(const short8*)&VHI[(dt * 16 + tl) * 72 + q * 8];
      short8 va1 = *(const short8*)&VHI[(dt * 16 + tl) * 72 + 32 + q * 8];
      f32x4 z = oacc[dt];
      z = __builtin_amdgcn_mfma_f32_16x16x32_bf16(va0, c0.s, z, 0, 0, 0);
      z = __builtin_amdgcn_mfma_f32_16x16x32_bf16(va1, c1.s, z, 0, 0, 0);
      oacc[dt] = z;
    }
  }

  // --- merge 3 streams in LDS; write o fp32 [b*4096+i][128]
  __syncthreads();
  float* OM = (float*)lds;             // [3][64][36]
  float* ML = (float*)(lds + 27648);   // [3][ m[64] | l[64] ]
  {
    float* om = OM + ((size_t)(strm * 64 + w * 16 + tl)) * 36;
    *(f32x4*)&om[q * 4] = oacc[0];        // d = q*4+r
    *(f32x4*)&om[16 + q * 4] = oacc[1];   // d = 16+q*4+r
    if (q == 0) {
      ML[strm * 128 + w * 16 + tl] = m;
      ML[strm * 128 + 64 + w * 16 + tl] = l;
    }
  }
  __syncthreads();
  const int b = bh >> 2, h = bh & 3;
#pragma unroll
  for (int pass = 0; pass < 3; ++pass) {
    const int idx = tid + pass * 768;
    if (idx < 2048) {
      const int i = idx >> 5, d = idx & 31;
      const float m0 = ML[i], m1 = ML[128 + i], m2 = ML[256 + i];
      const float l0 = ML[64 + i], l1 = ML[192 + i], l2 = ML[320 + i];
      const float M = fmaxf(m0, fmaxf(m1, m2));
      const float w0 = exp2f(m0 - M), w1 = exp2f(m1 - M), w2 = exp2f(m2 - M);
      const float L = l0 * w0 + l1 * w1 + l2 * w2;
      const float val =
          (OM[i * 36 + d] * w0 + OM[(64 + i) * 36 + d] * w1 + OM[(128 + i) * 36 + d] * w2) / L;
      o[((size_t)(b * 4096) + i0 + i) * 128 + h * 32 + d] = val;
    }
  }
}

// ---------------------------------------------------------------------------
// Kernel 4: out = o(fp32) @ w_out + b_out. [8192,128]x[128,64]. 1024 blocks.
__global__ __launch_bounds__(256) void proj_kernel(const float* __restrict__ o,
                                                   const float* __restrict__ w,
                                                   const float* __restrict__ bias,
                                                   float* __restrict__ out) {
  const int tid = threadIdx.x;
  const int col = tid & 63;
  const int r = blockIdx.x * 8 + ((tid >> 6) << 1);
  const float* r0 = o + (size_t)r * 128;
  const float* r1 = r0 + 128;
  float a0 = bias[col], a1 = a0;
  for (int c = 0; c < 128; c += 4) {
    const float4 x0 = *(const float4*)&r0[c];
    const float4 x1 = *(const float4*)&r1[c];
    const float w0 = w[(size_t)c * 64 + col];
    const float w1 = w[(size_t)(c + 1) * 64 + col];
    const float w2 = w[(size_t)(c + 2) * 64 + col];
    const float w3 = w[(size_t)(c + 3) * 64 + col];
    a0 = fmaf(x0.x, w0, a0); a0 = fmaf(x0.y, w1, a0);
    a0 = fmaf(x0.z, w2, a0); a0 = fmaf(x0.w, w3, a0);
    a1 = fmaf(x1.x, w0, a1); a1 = fmaf(x1.y, w1, a1);
    a1 = fmaf(x1.z, w2, a1); a1 = fmaf(x1.w, w3, a1);
  }
  out[(size_t)r * 64 + col] = a0;
  out[(size_t)(r + 1) * 64 + col] = a1;
}

// ---------------------------------------------------------------------------
extern "C" void kernel_launch(void* const* d_in, const int* in_sizes, int n_in,
                              void* d_out, int out_size, void* d_ws, size_t ws_size,
                              hipStream_t stream) {
  const float* input = (const float*)d_in[0];
  const float* w_qkv = (const float*)d_in[1];
  const float* w_out = (const float*)d_in[2];
  const float* b_out = (const float*)d_in[3];

  char* W = (char*)d_ws;
  float* qf = (float*)(W + 0);
  float* kf = (float*)(W + (4u << 20));   // reused as o fp32 after norm
  ushort* khg = (ushort*)(W + (8u << 20));
  ushort* klg = (ushort*)(W + (10u << 20));
  ushort* vhg = (ushort*)(W + (12u << 20));
  float* stats = (float*)(W + (14u << 20));
  float* ssumg = stats;
  float* ssqg = stats + 512;
  float* ob = kf;  // alias: kf dead after norm_kernel
  float* out = (float*)d_out;

  hipMemsetAsync(stats, 0, 1024 * sizeof(float), stream);
  hipLaunchKernelGGL(qkv_kernel, dim3(768), dim3(256), 0, stream, input, w_qkv, qf, kf,
                     vhg, ssumg, ssqg);
  hipLaunchKernelGGL(norm_kernel, dim3(256), dim3(256), 0, stream, qf, kf, khg, klg,
                     ssumg, ssqg);
  hipLaunchKernelGGL(attn_kernel, dim3(512), dim3(768), 0, stream, (const uint32_t*)qf,
                     khg, klg, vhg, ob);
  hipLaunchKernelGGL(proj_kernel, dim3(1024), dim3(256), 0, stream, ob, w_out, b_out, out);
}

// Round 4
// 148.976 us; speedup vs baseline: 6.0329x; 1.1697x over previous
//
#include <hip/hip_runtime.h>
#include <math.h>
#include <stdint.h>

// B=2, S=4096, H=4, D=32, C=64. SCALE=16 folded as 16*log2(e) into q (base-2 softmax).
//
// ws layout (bytes), total 14 MB + 4 KB:
//   0    : qf fp32 [8][4096][32]  -> packed uint32 (hi<<16|lo) in place by norm
//   4 MB : kf fp32 [8][4096][32]  -> dead after norm; REUSED as o fp32 [8192][128]
//   8 MB : k_hi ushort [8][4096][32]
//   10 MB: k_lo ushort [8][4096][32]
//   12 MB: v_hi ushort [8][32][4096]
//   14 MB: stats fp32 sum[512], sumsq[512]

typedef __attribute__((ext_vector_type(8))) short short8;
typedef __attribute__((ext_vector_type(4))) float f32x4;

#define QSCALE 23.083120654223414f /* 16 * log2(e) */

#if __has_builtin(__builtin_amdgcn_exp2f)
#define EXP2F(x) __builtin_amdgcn_exp2f(x)
#else
#define EXP2F(x) exp2f(x)
#endif

__device__ inline uint32_t pack_hilo(float y) {
  uint32_t uy = __float_as_uint(y);
  uint32_t hb = (uy + 0x7fffu + ((uy >> 16) & 1u)) >> 16;  // RNE bf16
  float hf = __uint_as_float(hb << 16);
  float r = y - hf;
  uint32_t ur = __float_as_uint(r);
  uint32_t lb = (ur + 0x7fffu + ((ur >> 16) & 1u)) >> 16;
  return (hb << 16) | (lb & 0xffffu);
}

__device__ inline ushort f32_to_bf16(float y) {
  uint32_t uy = __float_as_uint(y);
  return (ushort)((uy + 0x7fffu + ((uy >> 16) & 1u)) >> 16);
}

__device__ inline float bpermf(int addr, float v) {
  return __int_as_float(__builtin_amdgcn_ds_bpermute(addr, __float_as_int(v)));
}

// ---------------------------------------------------------------------------
// Kernel 1: qkv = input @ w_qkv. q,k -> fp32 [bh][s][32]; v -> bf16-hi ushort
// [bh][32][4096]. Accumulates per-(tensor,bh,d) sum/sumsq for q,k.
__global__ __launch_bounds__(256) void qkv_kernel(const float* __restrict__ in,
                                                  const float* __restrict__ w,
                                                  float* __restrict__ qf,
                                                  float* __restrict__ kf,
                                                  ushort* __restrict__ vhg,
                                                  float* __restrict__ ssumg,
                                                  float* __restrict__ ssqg) {
  __shared__ float As[64][65];
  __shared__ float Bs[64][68];
  __shared__ float ssum[64], ssq[64];
  const int ctile = blockIdx.x % 6;
  const int stile = blockIdx.x / 6;
  const int tid = threadIdx.x;
  const int row0 = stile * 64;
  const int sel = ctile >> 1;  // 0=q 1=k 2=v

  if (tid < 64) { ssum[tid] = 0.f; ssq[tid] = 0.f; }
  for (int idx = tid; idx < 64 * 64; idx += 256) {
    int s = idx >> 6, c = idx & 63;
    As[s][c] = in[(size_t)(row0 + s) * 64 + c];
  }
  for (int idx = tid; idx < 64 * 64; idx += 256) {
    int c = idx >> 6, ch = idx & 63;
    Bs[c][ch] = w[(size_t)c * 384 + ctile * 64 + ch];
  }
  __syncthreads();

  const int ts = tid >> 4, tc = tid & 15;
  float acc[4][4] = {};
  for (int c = 0; c < 64; ++c) {
    float av[4];
#pragma unroll
    for (int a = 0; a < 4; ++a) av[a] = As[ts * 4 + a][c];
    const float4 bv4 = *(const float4*)&Bs[c][tc * 4];
    const float bv[4] = {bv4.x, bv4.y, bv4.z, bv4.w};
#pragma unroll
    for (int a = 0; a < 4; ++a)
#pragma unroll
      for (int cc = 0; cc < 4; ++cc) acc[a][cc] = fmaf(av[a], bv[cc], acc[a][cc]);
  }

  const int b = row0 >> 12;
  const int sl = (row0 & 4095) + ts * 4;
  const int chg0 = ctile * 64 + tc * 4;

  if (sel < 2) {
    const int hd0 = chg0 & 127;
    const int h = hd0 >> 5, d0 = hd0 & 31;
    float* dst = (sel == 0 ? qf : kf) + ((size_t)(b * 4 + h) * 4096) * 32 + d0;
#pragma unroll
    for (int a = 0; a < 4; ++a) {
      float4 st = make_float4(acc[a][0], acc[a][1], acc[a][2], acc[a][3]);
      *(float4*)&dst[(size_t)(sl + a) * 32] = st;
    }
#pragma unroll
    for (int cc = 0; cc < 4; ++cc) {
      float sm = acc[0][cc] + acc[1][cc] + acc[2][cc] + acc[3][cc];
      float sq = acc[0][cc] * acc[0][cc] + acc[1][cc] * acc[1][cc] +
                 acc[2][cc] * acc[2][cc] + acc[3][cc] * acc[3][cc];
      atomicAdd(&ssum[tc * 4 + cc], sm);
      atomicAdd(&ssq[tc * 4 + cc], sq);
    }
    __syncthreads();
    if (tid < 64) {
      const int chg = ctile * 64 + tid;
      const int gidx = sel * 256 + b * 128 + (chg & 127);
      atomicAdd(&ssumg[gidx], ssum[tid]);
      atomicAdd(&ssqg[gidx], ssq[tid]);
    }
  } else {
    // v: bf16 hi only, [bh][d][s]
#pragma unroll
    for (int cc = 0; cc < 4; ++cc) {
      const int hd = (chg0 + cc) & 127;
      const int h = hd >> 5, d = hd & 31;
      ushort4 st;
      st.x = f32_to_bf16(acc[0][cc]);
      st.y = f32_to_bf16(acc[1][cc]);
      st.z = f32_to_bf16(acc[2][cc]);
      st.w = f32_to_bf16(acc[3][cc]);
      *(ushort4*)&vhg[((size_t)(b * 4 + h) * 32 + d) * 4096 + sl] = st;
    }
  }
}

// ---------------------------------------------------------------------------
// Kernel 2: standardize. q: fold QSCALE, pack hi/lo uint32 in place.
// k: write separate k_hi / k_lo ushort buffers. grid 256 blocks.
__global__ __launch_bounds__(256) void norm_kernel(float* __restrict__ qf,
                                                   const float* __restrict__ kf,
                                                   ushort* __restrict__ khg,
                                                   ushort* __restrict__ klg,
                                                   const float* __restrict__ ssumg,
                                                   const float* __restrict__ ssqg) {
  const int bx = blockIdx.x;
  const int tensor = bx >> 7;
  const int rem = bx & 127;
  const int bh = rem >> 4;
  const int s0 = (rem & 15) * 256;
  const int tid = threadIdx.x;
  const int d0 = (tid & 7) * 4;
  const int sbase = tensor * 256 + bh * 32 + d0;
  const float scale = tensor ? 1.0f : QSCALE;
  float mean[4], inv[4];
#pragma unroll
  for (int e = 0; e < 4; ++e) {
    float mu = ssumg[sbase + e] * (1.f / 4096.f);
    float var = ssqg[sbase + e] * (1.f / 4096.f) - mu * mu;
    mean[e] = mu;
    inv[e] = rsqrtf(var + 1e-5f) * scale;
  }
  if (tensor == 0) {
    float* src = qf + ((size_t)bh * 4096 + s0) * 32;
#pragma unroll
    for (int i = 0; i < 8; ++i) {
      const int s = (tid + i * 256) >> 3;
      float* p = &src[(size_t)s * 32 + d0];
      float4 x = *(const float4*)p;
      uint4 st;
      st.x = pack_hilo((x.x - mean[0]) * inv[0]);
      st.y = pack_hilo((x.y - mean[1]) * inv[1]);
      st.z = pack_hilo((x.z - mean[2]) * inv[2]);
      st.w = pack_hilo((x.w - mean[3]) * inv[3]);
      *(uint4*)p = st;
    }
  } else {
    const float* src = kf + ((size_t)bh * 4096 + s0) * 32;
    ushort* dh = khg + ((size_t)bh * 4096 + s0) * 32 + d0;
    ushort* dl = klg + ((size_t)bh * 4096 + s0) * 32 + d0;
#pragma unroll
    for (int i = 0; i < 8; ++i) {
      const int s = (tid + i * 256) >> 3;
      float4 x = *(const float4*)&src[(size_t)s * 32 + d0];
      float y[4] = {(x.x - mean[0]) * inv[0], (x.y - mean[1]) * inv[1],
                    (x.z - mean[2]) * inv[2], (x.w - mean[3]) * inv[3]};
      ushort4 hi, lo;
      ushort* hp = (ushort*)&hi;
      ushort* lp = (ushort*)&lo;
#pragma unroll
      for (int e = 0; e < 4; ++e) {
        ushort h = f32_to_bf16(y[e]);
        hp[e] = h;
        lp[e] = f32_to_bf16(y[e] - __uint_as_float((uint32_t)h << 16));
      }
      *(ushort4*)&dh[(size_t)s * 32] = hi;
      *(ushort4*)&dl[(size_t)s * 32] = lo;
    }
  }
}

// ---------------------------------------------------------------------------
// Kernel 3: flash attention, S^T-orientation (rows-in-lanes).
// grid 512 = 8 bh * 64 i-tiles; 1024 threads = 4 j-streams * 4 waves.
// Stream s covers j-tiles [16s, 16s+16) — uniform, no tail.
//
// S^T = K·Q^T with sigma row permutation (K rows stored permuted) so each
// lane's 16 P values are exactly the in-lane B-fragment for PV (O^T=V^T·P^T).
// LDS XOR chunk swizzle: K rows 64B, chunk ^= (row>>1)&3; V rows 128B,
// chunk ^= row&7 — b128 reads/writes hit 8 distinct 16B bank groups per
// 8-lane group (conflict-free).
__global__ __launch_bounds__(1024, 8) void attn_kernel(const uint32_t* __restrict__ qp,
                                                       const ushort* __restrict__ khg,
                                                       const ushort* __restrict__ klg,
                                                       const ushort* __restrict__ vhg,
                                                       float* __restrict__ o) {
  __shared__ char lds[49152];  // 4 streams * 12288 B; merge region unions

  const int tid = threadIdx.x;
  const int strm = tid >> 8;
  const int st = tid & 255;
  const int w = st >> 6;
  const int lane = tid & 63;
  const int q = lane >> 4, tl = lane & 15;
  const int bh = blockIdx.x >> 6;
  const int i0 = (blockIdx.x & 63) * 64;

  ushort* KHI = (ushort*)lds + strm * 6144;  // [64][32] rows sigma-permuted, swizzled
  ushort* KLO = KHI + 2048;                  // [64][32]
  ushort* VHI = KHI + 4096;                  // [32][64] = [d][j], swizzled

  // --- q B-frags: B[k=d=q*8+jj][n=i=tl], hi/lo (same for all streams)
  const int irow = i0 + w * 16 + tl;
  const uint32_t* qptr = qp + ((size_t)bh * 4096 + irow) * 32 + q * 8;
  uint4 qa = *(const uint4*)qptr;
  uint4 qb = *(const uint4*)(qptr + 4);
  short8 qhi, qlo;
  {
    uint32_t u[8] = {qa.x, qa.y, qa.z, qa.w, qb.x, qb.y, qb.z, qb.w};
#pragma unroll
    for (int j = 0; j < 8; ++j) { qhi[j] = (short)(u[j] >> 16); qlo[j] = (short)(u[j] & 0xffff); }
  }

  // --- precomputed cross-lane bpermute byte addresses (lane^16, lane^32)
  const int bp16 = (lane ^ 16) << 2;
  const int bp32 = (lane ^ 32) << 2;

  // --- staging addresses (fixed per thread; only j0 advances)
  const int jr = st >> 2, ck = st & 3;  // k: 64 rows x 4 chunks of 16B
  const int sig = ((((jr >> 5) & 1) * 2 + ((jr >> 2) & 1)) << 4) +
                  ((((jr >> 3) & 3)) << 2) + (jr & 3);  // sigma row permutation
  const int ckp = ck ^ ((sig >> 1) & 3);                // physical chunk (XOR swizzle)
  const ushort* khsrc = khg + ((size_t)bh * 4096 + jr) * 32 + ck * 8;
  const ushort* klsrc = klg + ((size_t)bh * 4096 + jr) * 32 + ck * 8;
  ushort* khdst = &KHI[sig * 32 + ckp * 8];
  ushort* kldst = &KLO[sig * 32 + ckp * 8];
  const int dr = st >> 3, cv = st & 7;  // v: 32 rows x 8 chunks of 16B
  const int cvp = cv ^ (dr & 7);
  const ushort* vsrc = vhg + ((size_t)bh * 32 + dr) * 4096 + cv * 8;
  ushort* vdst = &VHI[dr * 64 + cvp * 8];

  // --- loop-invariant LDS read offsets (swizzle folded in)
  const int koff = tl * 32 + (q ^ ((tl >> 1) & 3)) * 8;          // + jt*512
  const int voff0 = tl * 64 + (q ^ (tl & 7)) * 8;                // + dt*1024
  const int voff1 = tl * 64 + ((q + 4) ^ (tl & 7)) * 8;          // + dt*1024

  f32x4 oacc[2] = {{0.f, 0.f, 0.f, 0.f}, {0.f, 0.f, 0.f, 0.f}};
  float m = -INFINITY, l = 0.f;

  for (int it = 0; it < 16; ++it) {
    const int j0 = strm * 1024 + it * 64;
    __syncthreads();
    *(uint4*)khdst = *(const uint4*)(khsrc + (size_t)j0 * 32);
    *(uint4*)kldst = *(const uint4*)(klsrc + (size_t)j0 * 32);
    *(uint4*)vdst = *(const uint4*)(vsrc + j0);
    __syncthreads();

    // --- S^T tiles: A = K rows (sigma-permuted), B = Q frags. 3 MFMAs/tile.
    f32x4 sc[4];
#pragma unroll
    for (int jt = 0; jt < 4; ++jt) {
      short8 kh = *(const short8*)&KHI[jt * 512 + koff];
      short8 kl = *(const short8*)&KLO[jt * 512 + koff];
      f32x4 z = {0.f, 0.f, 0.f, 0.f};
      z = __builtin_amdgcn_mfma_f32_16x16x32_bf16(kh, qhi, z, 0, 0, 0);
      z = __builtin_amdgcn_mfma_f32_16x16x32_bf16(kh, qlo, z, 0, 0, 0);
      z = __builtin_amdgcn_mfma_f32_16x16x32_bf16(kl, qhi, z, 0, 0, 0);
      sc[jt] = z;
    }

    // --- online softmax, base-2; row i=tl spread over quads (q lanes)
    f32x4 vm = __builtin_elementwise_max(__builtin_elementwise_max(sc[0], sc[1]),
                                         __builtin_elementwise_max(sc[2], sc[3]));
    float mx = fmaxf(fmaxf(vm[0], vm[1]), fmaxf(vm[2], vm[3]));
    mx = fmaxf(mx, bpermf(bp16, mx));
    mx = fmaxf(mx, bpermf(bp32, mx));
    const float mn = fmaxf(m, mx);
    const float al = EXP2F(m - mn);
    m = mn;
#pragma unroll
    for (int jt = 0; jt < 4; ++jt) {
      f32x4 t = sc[jt] - mn;
#pragma unroll
      for (int r = 0; r < 4; ++r) sc[jt][r] = EXP2F(t[r]);
    }
    f32x4 vs = (sc[0] + sc[1]) + (sc[2] + sc[3]);
    float rs = (vs[0] + vs[1]) + (vs[2] + vs[3]);
    rs += bpermf(bp16, rs);
    rs += bpermf(bp32, rs);
    l = l * al + rs;
    oacc[0] *= al;
    oacc[1] *= al;

    // --- P -> bf16 (truncation; -2^-9 bias compensated in merge), in-lane
    uint32_t pk[8];
#pragma unroll
    for (int jt = 0; jt < 4; ++jt)
#pragma unroll
      for (int p = 0; p < 2; ++p)
        pk[jt * 2 + p] = __builtin_amdgcn_perm(__float_as_uint(sc[jt][2 * p + 1]),
                                               __float_as_uint(sc[jt][2 * p]), 0x07060302u);
    union { uint32_t u[4]; short8 s; } c0, c1;
    c0.u[0] = pk[0]; c0.u[1] = pk[1]; c0.u[2] = pk[2]; c0.u[3] = pk[3];
    c1.u[0] = pk[4]; c1.u[1] = pk[5]; c1.u[2] = pk[6]; c1.u[3] = pk[7];

    // --- PV: O^T = V^T · P^T. A = V rows d (b128, swizzled), B = P frags.
#pragma unroll
    for (int dt = 0; dt < 2; ++dt) {
      short8 va0 = *(const short8*)&VHI[dt * 1024 + voff0];
      short8 va1 = *(const short8*)&VHI[dt * 1024 + voff1];
      f32x4 z = oacc[dt];
      z = __builtin_amdgcn_mfma_f32_16x16x32_bf16(va0, c0.s, z, 0, 0, 0);
      z = __builtin_amdgcn_mfma_f32_16x16x32_bf16(va1, c1.s, z, 0, 0, 0);
      oacc[dt] = z;
    }
  }

  // --- merge 4 streams in LDS; write o fp32 [b*4096+i][128]
  __syncthreads();
  float* OM = (float*)lds;             // [4*64][36]
  float* ML = (float*)(lds + 36864);   // [4][ m[64] | l[64] ]
  {
    float* om = OM + ((size_t)(strm * 64 + w * 16 + tl)) * 36;
    *(f32x4*)&om[q * 4] = oacc[0];        // d = q*4+r
    *(f32x4*)&om[16 + q * 4] = oacc[1];   // d = 16+q*4+r
    if (q == 0) {
      ML[strm * 128 + w * 16 + tl] = m;
      ML[strm * 128 + 64 + w * 16 + tl] = l;
    }
  }
  __syncthreads();
  const int b = bh >> 2, h = bh & 3;
#pragma unroll
  for (int pass = 0; pass < 2; ++pass) {
    const int idx = tid + pass * 1024;
    const int i = idx >> 5, d = idx & 31;
    const float m0 = ML[i], m1 = ML[128 + i], m2 = ML[256 + i], m3 = ML[384 + i];
    const float l0 = ML[64 + i], l1 = ML[192 + i], l2 = ML[320 + i], l3 = ML[448 + i];
    const float M = fmaxf(fmaxf(m0, m1), fmaxf(m2, m3));
    const float w0 = EXP2F(m0 - M), w1 = EXP2F(m1 - M);
    const float w2 = EXP2F(m2 - M), w3 = EXP2F(m3 - M);
    const float L = l0 * w0 + l1 * w1 + l2 * w2 + l3 * w3;
    const float val = (OM[i * 36 + d] * w0 + OM[(64 + i) * 36 + d] * w1 +
                       OM[(128 + i) * 36 + d] * w2 + OM[(192 + i) * 36 + d] * w3) *
                      (1.001953125f / L);  // (1+2^-9): P truncation bias compensation
    o[((size_t)(b * 4096) + i0 + i) * 128 + h * 32 + d] = val;
  }
}

// ---------------------------------------------------------------------------
// Kernel 4: out = o(fp32) @ w_out + b_out. [8192,128]x[128,64]. 1024 blocks.
__global__ __launch_bounds__(256) void proj_kernel(const float* __restrict__ o,
                                                   const float* __restrict__ w,
                                                   const float* __restrict__ bias,
                                                   float* __restrict__ out) {
  const int tid = threadIdx.x;
  const int col = tid & 63;
  const int r = blockIdx.x * 8 + ((tid >> 6) << 1);
  const float* r0 = o + (size_t)r * 128;
  const float* r1 = r0 + 128;
  float a0 = bias[col], a1 = a0;
  for (int c = 0; c < 128; c += 4) {
    const float4 x0 = *(const float4*)&r0[c];
    const float4 x1 = *(const float4*)&r1[c];
    const float w0 = w[(size_t)c * 64 + col];
    const float w1 = w[(size_t)(c + 1) * 64 + col];
    const float w2 = w[(size_t)(c + 2) * 64 + col];
    const float w3 = w[(size_t)(c + 3) * 64 + col];
    a0 = fmaf(x0.x, w0, a0); a0 = fmaf(x0.y, w1, a0);
    a0 = fmaf(x0.z, w2, a0); a0 = fmaf(x0.w, w3, a0);
    a1 = fmaf(x1.x, w0, a1); a1 = fmaf(x1.y, w1, a1);
    a1 = fmaf(x1.z, w2, a1); a1 = fmaf(x1.w, w3, a1);
  }
  out[(size_t)r * 64 + col] = a0;
  out[(size_t)(r + 1) * 64 + col] = a1;
}

// ---------------------------------------------------------------------------
extern "C" void kernel_launch(void* const* d_in, const int* in_sizes, int n_in,
                              void* d_out, int out_size, void* d_ws, size_t ws_size,
                              hipStream_t stream) {
  const float* input = (const float*)d_in[0];
  const float* w_qkv = (const float*)d_in[1];
  const float* w_out = (const float*)d_in[2];
  const float* b_out = (const float*)d_in[3];

  char* W = (char*)d_ws;
  float* qf = (float*)(W + 0);
  float* kf = (float*)(W + (4u << 20));   // reused as o fp32 after norm
  ushort* khg = (ushort*)(W + (8u << 20));
  ushort* klg = (ushort*)(W + (10u << 20));
  ushort* vhg = (ushort*)(W + (12u << 20));
  float* stats = (float*)(W + (14u << 20));
  float* ssumg = stats;
  float* ssqg = stats + 512;
  float* ob = kf;  // alias: kf dead after norm_kernel
  float* out = (float*)d_out;

  hipMemsetAsync(stats, 0, 1024 * sizeof(float), stream);
  hipLaunchKernelGGL(qkv_kernel, dim3(768), dim3(256), 0, stream, input, w_qkv, qf, kf,
                     vhg, ssumg, ssqg);
  hipLaunchKernelGGL(norm_kernel, dim3(256), dim3(256), 0, stream, qf, kf, khg, klg,
                     ssumg, ssqg);
  hipLaunchKernelGGL(attn_kernel, dim3(512), dim3(1024), 0, stream, (const uint32_t*)qf,
                     khg, klg, vhg, ob);
  hipLaunchKernelGGL(proj_kernel, dim3(1024), dim3(256), 0, stream, ob, w_out, b_out, out);
}

// Round 5
// 144.699 us; speedup vs baseline: 6.2112x; 1.0296x over previous
//
#include <hip/hip_runtime.h>
#include <math.h>
#include <stdint.h>

// B=2, S=4096, H=4, D=32, C=64. SCALE=16 folded as 16*log2(e) into q (base-2 softmax).
//
// ws layout (bytes), total < 15 MB:
//   0    : qf fp32 [8][4096][32]   (raw q; standardized inside attn)
//   4 MB : kf fp32 [8][4096][32]   -> dead after norm; REUSED as o fp32 [8192][128]
//   8 MB : k_hi ushort [8][4096][32]
//   10 MB: k_lo ushort [8][4096][32]
//   12 MB: v_hi ushort [8][32][4096]
//   14 MB: psum fp32 [2][2][128][64] (128 KB)  -- per-block partial sums (no atomics)
//   14.125 MB: psq  fp32 [2][2][128][64] (128 KB)
//   14.25 MB : qA[256], qB[256] fp32  (q standardize tables: y = x*A + B)

typedef __attribute__((ext_vector_type(8))) short short8;
typedef __attribute__((ext_vector_type(4))) float f32x4;

#define QSCALE 23.083120654223414f /* 16 * log2(e) */

#if __has_builtin(__builtin_amdgcn_exp2f)
#define EXP2F(x) __builtin_amdgcn_exp2f(x)
#else
#define EXP2F(x) exp2f(x)
#endif

__device__ inline uint32_t pack_hilo(float y) {
  uint32_t uy = __float_as_uint(y);
  uint32_t hb = (uy + 0x7fffu + ((uy >> 16) & 1u)) >> 16;  // RNE bf16
  float hf = __uint_as_float(hb << 16);
  float r = y - hf;
  uint32_t ur = __float_as_uint(r);
  uint32_t lb = (ur + 0x7fffu + ((ur >> 16) & 1u)) >> 16;
  return (hb << 16) | (lb & 0xffffu);
}

__device__ inline ushort f32_to_bf16(float y) {
  uint32_t uy = __float_as_uint(y);
  return (ushort)((uy + 0x7fffu + ((uy >> 16) & 1u)) >> 16);
}

__device__ inline float bpermf(int addr, float v) {
  return __int_as_float(__builtin_amdgcn_ds_bpermute(addr, __float_as_int(v)));
}

// ---------------------------------------------------------------------------
// Kernel 1: qkv = input @ w_qkv. q,k -> fp32 [bh][s][32]; v -> bf16-hi ushort
// [bh][32][4096]. Per-block stat partials to unique slots (no atomics/memset).
__global__ __launch_bounds__(256) void qkv_kernel(const float* __restrict__ in,
                                                  const float* __restrict__ w,
                                                  float* __restrict__ qf,
                                                  float* __restrict__ kf,
                                                  ushort* __restrict__ vhg,
                                                  float* __restrict__ psum,
                                                  float* __restrict__ psq) {
  __shared__ float As[64][68];
  __shared__ float Bs[64][68];
  __shared__ float ssum[64], ssq[64];
  const int ctile = blockIdx.x % 6;
  const int stile = blockIdx.x / 6;
  const int tid = threadIdx.x;
  const int row0 = stile * 64;
  const int sel = ctile >> 1;  // 0=q 1=k 2=v

  if (tid < 64) { ssum[tid] = 0.f; ssq[tid] = 0.f; }
  for (int idx = tid; idx < 64 * 64; idx += 256) {
    int s = idx >> 6, c = idx & 63;
    As[s][c] = in[(size_t)(row0 + s) * 64 + c];
  }
  for (int idx = tid; idx < 64 * 64; idx += 256) {
    int c = idx >> 6, ch = idx & 63;
    Bs[c][ch] = w[(size_t)c * 384 + ctile * 64 + ch];
  }
  __syncthreads();

  const int ts = tid >> 4, tc = tid & 15;
  float acc[4][4] = {};
  for (int c = 0; c < 64; c += 4) {
    float4 av[4];
#pragma unroll
    for (int a = 0; a < 4; ++a) av[a] = *(const float4*)&As[ts * 4 + a][c];
    const float4 b0 = *(const float4*)&Bs[c + 0][tc * 4];
    const float4 b1 = *(const float4*)&Bs[c + 1][tc * 4];
    const float4 b2 = *(const float4*)&Bs[c + 2][tc * 4];
    const float4 b3 = *(const float4*)&Bs[c + 3][tc * 4];
    const float bm[4][4] = {{b0.x, b0.y, b0.z, b0.w},
                            {b1.x, b1.y, b1.z, b1.w},
                            {b2.x, b2.y, b2.z, b2.w},
                            {b3.x, b3.y, b3.z, b3.w}};
#pragma unroll
    for (int a = 0; a < 4; ++a) {
      const float aw[4] = {av[a].x, av[a].y, av[a].z, av[a].w};
#pragma unroll
      for (int j = 0; j < 4; ++j)
#pragma unroll
        for (int cc = 0; cc < 4; ++cc) acc[a][cc] = fmaf(aw[j], bm[j][cc], acc[a][cc]);
    }
  }

  const int b = row0 >> 12;
  const int sl = (row0 & 4095) + ts * 4;
  const int chg0 = ctile * 64 + tc * 4;

  if (sel < 2) {
    const int hd0 = chg0 & 127;
    const int h = hd0 >> 5, d0 = hd0 & 31;
    float* dst = (sel == 0 ? qf : kf) + ((size_t)(b * 4 + h) * 4096) * 32 + d0;
#pragma unroll
    for (int a = 0; a < 4; ++a) {
      float4 st = make_float4(acc[a][0], acc[a][1], acc[a][2], acc[a][3]);
      *(float4*)&dst[(size_t)(sl + a) * 32] = st;
    }
#pragma unroll
    for (int cc = 0; cc < 4; ++cc) {
      float sm = acc[0][cc] + acc[1][cc] + acc[2][cc] + acc[3][cc];
      float sq = acc[0][cc] * acc[0][cc] + acc[1][cc] * acc[1][cc] +
                 acc[2][cc] * acc[2][cc] + acc[3][cc] * acc[3][cc];
      atomicAdd(&ssum[tc * 4 + cc], sm);  // LDS-only atomics (cheap)
      atomicAdd(&ssq[tc * 4 + cc], sq);
    }
    __syncthreads();
    if (tid < 64) {
      const int ch = (ctile & 1) * 64 + tid;
      const int idx = (((sel * 2 + b) * 128) + ch) * 64 + (stile & 63);
      psum[idx] = ssum[tid];
      psq[idx] = ssq[tid];
    }
  } else {
    // v: bf16 hi only, [bh][d][s]
#pragma unroll
    for (int cc = 0; cc < 4; ++cc) {
      const int hd = (chg0 + cc) & 127;
      const int h = hd >> 5, d = hd & 31;
      ushort4 st;
      st.x = f32_to_bf16(acc[0][cc]);
      st.y = f32_to_bf16(acc[1][cc]);
      st.z = f32_to_bf16(acc[2][cc]);
      st.w = f32_to_bf16(acc[3][cc]);
      *(ushort4*)&vhg[((size_t)(b * 4 + h) * 32 + d) * 4096 + sl] = st;
    }
  }
}

// ---------------------------------------------------------------------------
// Kernel 2: grid 129. Blocks 0..127: finalize k stats + standardize k ->
// k_hi/k_lo (bh = bx>>4, 256-s chunk = bx&15). Block 128: q stat tables
// qA = inv*QSCALE, qB = -mean*inv*QSCALE.
__global__ __launch_bounds__(256) void norm_kernel(const float* __restrict__ kf,
                                                   ushort* __restrict__ khg,
                                                   ushort* __restrict__ klg,
                                                   const float* __restrict__ psum,
                                                   const float* __restrict__ psq,
                                                   float* __restrict__ qA,
                                                   float* __restrict__ qB) {
  const int bx = blockIdx.x;
  const int tid = threadIdx.x;
  if (bx == 128) {
    // q tables: thread t -> (b = t>>7, ch = t&127); index t == bh*32+d
    const int base = (((tid >> 7) * 128) + (tid & 127)) * 64;
    float sm = 0.f, sq = 0.f;
#pragma unroll 8
    for (int e = 0; e < 64; ++e) {
      sm += psum[base + e];
      sq += psq[base + e];
    }
    const float mu = sm * (1.f / 4096.f);
    const float inv = rsqrtf(sq * (1.f / 4096.f) - mu * mu + 1e-5f) * QSCALE;
    qA[tid] = inv;
    qB[tid] = -mu * inv;
    return;
  }
  __shared__ float red[2][32][8];
  __shared__ float kA[32], kB[32];
  const int bh = bx >> 4;
  const int s0 = (bx & 15) * 256;
  {  // k stat reduce for this bh's 32 channels
    const int d = tid >> 3, p = tid & 7;
    const int base = ((2 + (bh >> 2)) * 128 + (bh & 3) * 32 + d) * 64 + p * 8;
    float sm = 0.f, sq = 0.f;
#pragma unroll
    for (int e = 0; e < 8; ++e) {
      sm += psum[base + e];
      sq += psq[base + e];
    }
    red[0][d][p] = sm;
    red[1][d][p] = sq;
  }
  __syncthreads();
  if (tid < 32) {
    float sm = 0.f, sq = 0.f;
#pragma unroll
    for (int e = 0; e < 8; ++e) {
      sm += red[0][tid][e];
      sq += red[1][tid][e];
    }
    const float mu = sm * (1.f / 4096.f);
    const float inv = rsqrtf(sq * (1.f / 4096.f) - mu * mu + 1e-5f);
    kA[tid] = inv;
    kB[tid] = -mu * inv;
  }
  __syncthreads();

  const int d0 = (tid & 7) * 4;
  const float A0 = kA[d0], A1 = kA[d0 + 1], A2 = kA[d0 + 2], A3 = kA[d0 + 3];
  const float B0 = kB[d0], B1 = kB[d0 + 1], B2 = kB[d0 + 2], B3 = kB[d0 + 3];
  const float* src = kf + ((size_t)bh * 4096 + s0) * 32;
  ushort* dh = khg + ((size_t)bh * 4096 + s0) * 32 + d0;
  ushort* dl = klg + ((size_t)bh * 4096 + s0) * 32 + d0;
#pragma unroll
  for (int i = 0; i < 8; ++i) {
    const int s = (tid + i * 256) >> 3;
    float4 x = *(const float4*)&src[(size_t)s * 32 + d0];
    float y[4] = {fmaf(x.x, A0, B0), fmaf(x.y, A1, B1), fmaf(x.z, A2, B2), fmaf(x.w, A3, B3)};
    ushort4 hi, lo;
    ushort* hp = (ushort*)&hi;
    ushort* lp = (ushort*)&lo;
#pragma unroll
    for (int e = 0; e < 4; ++e) {
      uint32_t pk = pack_hilo(y[e]);
      hp[e] = (ushort)(pk >> 16);
      lp[e] = (ushort)(pk & 0xffff);
    }
    *(ushort4*)&dh[(size_t)s * 32] = hi;
    *(ushort4*)&dl[(size_t)s * 32] = lo;
  }
}

// ---------------------------------------------------------------------------
// Kernel 3: flash attention, S^T-orientation (rows-in-lanes), register-
// prefetched staging. grid 512 = 8 bh * 64 i-tiles; 1024 thr = 4 j-streams.
// q standardization folded in (y = x*qA + qB, hi/lo split per block).
__global__ __launch_bounds__(1024, 8) void attn_kernel(const float* __restrict__ qf,
                                                       const float* __restrict__ qA,
                                                       const float* __restrict__ qB,
                                                       const ushort* __restrict__ khg,
                                                       const ushort* __restrict__ klg,
                                                       const ushort* __restrict__ vhg,
                                                       float* __restrict__ o) {
  __shared__ char lds[49152];  // 4 streams * 12288 B; merge region unions

  const int tid = threadIdx.x;
  const int strm = tid >> 8;
  const int st = tid & 255;
  const int w = st >> 6;
  const int lane = tid & 63;
  const int q = lane >> 4, tl = lane & 15;
  const int bh = blockIdx.x >> 6;
  const int i0 = (blockIdx.x & 63) * 64;

  ushort* KHI = (ushort*)lds + strm * 6144;  // [64][32] rows sigma-permuted, swizzled
  ushort* KLO = KHI + 2048;                  // [64][32]
  ushort* VHI = KHI + 4096;                  // [32][64] = [d][j], swizzled

  // --- q: load fp32, standardize (x*A+B), split hi/lo. B[k=d=q*8+jj][n=i=tl]
  const int irow = i0 + w * 16 + tl;
  const float* qptr = qf + ((size_t)bh * 4096 + irow) * 32 + q * 8;
  short8 qhi, qlo;
  {
    const float4 xa = *(const float4*)qptr;
    const float4 xb = *(const float4*)(qptr + 4);
    const float4 Aa = *(const float4*)&qA[bh * 32 + q * 8];
    const float4 Ab = *(const float4*)&qA[bh * 32 + q * 8 + 4];
    const float4 Ba = *(const float4*)&qB[bh * 32 + q * 8];
    const float4 Bb = *(const float4*)&qB[bh * 32 + q * 8 + 4];
    const float y[8] = {fmaf(xa.x, Aa.x, Ba.x), fmaf(xa.y, Aa.y, Ba.y),
                        fmaf(xa.z, Aa.z, Ba.z), fmaf(xa.w, Aa.w, Ba.w),
                        fmaf(xb.x, Ab.x, Bb.x), fmaf(xb.y, Ab.y, Bb.y),
                        fmaf(xb.z, Ab.z, Bb.z), fmaf(xb.w, Ab.w, Bb.w)};
#pragma unroll
    for (int j = 0; j < 8; ++j) {
      uint32_t pk = pack_hilo(y[j]);
      qhi[j] = (short)(pk >> 16);
      qlo[j] = (short)(pk & 0xffff);
    }
  }

  // --- precomputed cross-lane bpermute byte addresses (lane^16, lane^32)
  const int bp16 = (lane ^ 16) << 2;
  const int bp32 = (lane ^ 32) << 2;

  // --- staging addresses (fixed per thread; only j0 advances)
  const int jr = st >> 2, ck = st & 3;  // k: 64 rows x 4 chunks of 16B
  const int sig = ((((jr >> 5) & 1) * 2 + ((jr >> 2) & 1)) << 4) +
                  ((((jr >> 3) & 3)) << 2) + (jr & 3);  // sigma row permutation
  const int ckp = ck ^ ((sig >> 1) & 3);                // physical chunk (XOR swizzle)
  const ushort* khsrc = khg + ((size_t)bh * 4096 + jr) * 32 + ck * 8;
  const ushort* klsrc = klg + ((size_t)bh * 4096 + jr) * 32 + ck * 8;
  ushort* khdst = &KHI[sig * 32 + ckp * 8];
  ushort* kldst = &KLO[sig * 32 + ckp * 8];
  const int dr = st >> 3, cv = st & 7;  // v: 32 rows x 8 chunks of 16B
  const int cvp = cv ^ (dr & 7);
  const ushort* vsrc = vhg + ((size_t)bh * 32 + dr) * 4096 + cv * 8;
  ushort* vdst = &VHI[dr * 64 + cvp * 8];

  // --- loop-invariant LDS read offsets (swizzle folded in)
  const int koff = tl * 32 + (q ^ ((tl >> 1) & 3)) * 8;          // + jt*512
  const int voff0 = tl * 64 + (q ^ (tl & 7)) * 8;                // + dt*1024
  const int voff1 = tl * 64 + ((q + 4) ^ (tl & 7)) * 8;          // + dt*1024

  f32x4 oacc[2] = {{0.f, 0.f, 0.f, 0.f}, {0.f, 0.f, 0.f, 0.f}};
  float m = -INFINITY, l = 0.f;

  // --- register prefetch of tile 0
  uint4 rk = *(const uint4*)(khsrc + (size_t)(strm * 1024) * 32);
  uint4 rl = *(const uint4*)(klsrc + (size_t)(strm * 1024) * 32);
  uint4 rv = *(const uint4*)(vsrc + strm * 1024);

  for (int it = 0; it < 16; ++it) {
    __syncthreads();  // prev iter's LDS readers done
    *(uint4*)khdst = rk;
    *(uint4*)kldst = rl;
    *(uint4*)vdst = rv;
    __syncthreads();
    if (it < 15) {  // prefetch next tile; latency overlaps compute below
      const int j0n = strm * 1024 + (it + 1) * 64;
      rk = *(const uint4*)(khsrc + (size_t)j0n * 32);
      rl = *(const uint4*)(klsrc + (size_t)j0n * 32);
      rv = *(const uint4*)(vsrc + j0n);
    }

    // --- S^T tiles: A = K rows (sigma-permuted), B = Q frags. 3 MFMAs/tile.
    f32x4 sc[4];
#pragma unroll
    for (int jt = 0; jt < 4; ++jt) {
      short8 kh = *(const short8*)&KHI[jt * 512 + koff];
      short8 kl = *(const short8*)&KLO[jt * 512 + koff];
      f32x4 z = {0.f, 0.f, 0.f, 0.f};
      z = __builtin_amdgcn_mfma_f32_16x16x32_bf16(kh, qhi, z, 0, 0, 0);
      z = __builtin_amdgcn_mfma_f32_16x16x32_bf16(kh, qlo, z, 0, 0, 0);
      z = __builtin_amdgcn_mfma_f32_16x16x32_bf16(kl, qhi, z, 0, 0, 0);
      sc[jt] = z;
    }

    // --- online softmax, base-2; row i=tl spread over quads (q lanes)
    f32x4 vm = __builtin_elementwise_max(__builtin_elementwise_max(sc[0], sc[1]),
                                         __builtin_elementwise_max(sc[2], sc[3]));
    float mx = fmaxf(fmaxf(vm[0], vm[1]), fmaxf(vm[2], vm[3]));
    mx = fmaxf(mx, bpermf(bp16, mx));
    mx = fmaxf(mx, bpermf(bp32, mx));
    const float mn = fmaxf(m, mx);
    const float al = EXP2F(m - mn);
    m = mn;
#pragma unroll
    for (int jt = 0; jt < 4; ++jt) {
      f32x4 t = sc[jt] - mn;
#pragma unroll
      for (int r = 0; r < 4; ++r) sc[jt][r] = EXP2F(t[r]);
    }
    f32x4 vs = (sc[0] + sc[1]) + (sc[2] + sc[3]);
    float rs = (vs[0] + vs[1]) + (vs[2] + vs[3]);
    rs += bpermf(bp16, rs);
    rs += bpermf(bp32, rs);
    l = l * al + rs;
    oacc[0] *= al;
    oacc[1] *= al;

    // --- P -> bf16 (truncation; -2^-9 bias compensated in merge), in-lane
    uint32_t pk[8];
#pragma unroll
    for (int jt = 0; jt < 4; ++jt)
#pragma unroll
      for (int p = 0; p < 2; ++p)
        pk[jt * 2 + p] = __builtin_amdgcn_perm(__float_as_uint(sc[jt][2 * p + 1]),
                                               __float_as_uint(sc[jt][2 * p]), 0x07060302u);
    union { uint32_t u[4]; short8 s; } c0, c1;
    c0.u[0] = pk[0]; c0.u[1] = pk[1]; c0.u[2] = pk[2]; c0.u[3] = pk[3];
    c1.u[0] = pk[4]; c1.u[1] = pk[5]; c1.u[2] = pk[6]; c1.u[3] = pk[7];

    // --- PV: O^T = V^T · P^T. A = V rows d (b128, swizzled), B = P frags.
#pragma unroll
    for (int dt = 0; dt < 2; ++dt) {
      short8 va0 = *(const short8*)&VHI[dt * 1024 + voff0];
      short8 va1 = *(const short8*)&VHI[dt * 1024 + voff1];
      f32x4 z = oacc[dt];
      z = __builtin_amdgcn_mfma_f32_16x16x32_bf16(va0, c0.s, z, 0, 0, 0);
      z = __builtin_amdgcn_mfma_f32_16x16x32_bf16(va1, c1.s, z, 0, 0, 0);
      oacc[dt] = z;
    }
  }

  // --- merge 4 streams in LDS; write o fp32 [b*4096+i][128]
  __syncthreads();
  float* OM = (float*)lds;             // [4*64][36]
  float* ML = (float*)(lds + 36864);   // [4][ m[64] | l[64] ]
  {
    float* om = OM + ((size_t)(strm * 64 + w * 16 + tl)) * 36;
    *(f32x4*)&om[q * 4] = oacc[0];        // d = q*4+r
    *(f32x4*)&om[16 + q * 4] = oacc[1];   // d = 16+q*4+r
    if (q == 0) {
      ML[strm * 128 + w * 16 + tl] = m;
      ML[strm * 128 + 64 + w * 16 + tl] = l;
    }
  }
  __syncthreads();
  const int b = bh >> 2, h = bh & 3;
#pragma unroll
  for (int pass = 0; pass < 2; ++pass) {
    const int idx = tid + pass * 1024;
    const int i = idx >> 5, d = idx & 31;
    const float m0 = ML[i], m1 = ML[128 + i], m2 = ML[256 + i], m3 = ML[384 + i];
    const float l0 = ML[64 + i], l1 = ML[192 + i], l2 = ML[320 + i], l3 = ML[448 + i];
    const float M = fmaxf(fmaxf(m0, m1), fmaxf(m2, m3));
    const float w0 = EXP2F(m0 - M), w1 = EXP2F(m1 - M);
    const float w2 = EXP2F(m2 - M), w3 = EXP2F(m3 - M);
    const float L = l0 * w0 + l1 * w1 + l2 * w2 + l3 * w3;
    const float val = (OM[i * 36 + d] * w0 + OM[(64 + i) * 36 + d] * w1 +
                       OM[(128 + i) * 36 + d] * w2 + OM[(192 + i) * 36 + d] * w3) *
                      (1.001953125f / L);  // (1+2^-9): P truncation bias compensation
    o[((size_t)(b * 4096) + i0 + i) * 128 + h * 32 + d] = val;
  }
}

// ---------------------------------------------------------------------------
// Kernel 4: out = o(fp32) @ w_out + b_out. [8192,128]x[128,64]. 1024 blocks.
// w staged transposed in LDS (XOR-swizzled granules, conflict-free b128 reads).
__global__ __launch_bounds__(256) void proj_kernel(const float* __restrict__ o,
                                                   const float* __restrict__ w,
                                                   const float* __restrict__ bias,
                                                   float* __restrict__ out) {
  __shared__ float wT[64 * 132];  // [col][c], 16B granule g = (c>>2)^((col>>3)&7)
  const int tid = threadIdx.x;
  for (int idx = tid; idx < 8192; idx += 256) {
    const int c = idx >> 6, col = idx & 63;
    const int g = (c >> 2) ^ ((col >> 3) & 7);
    wT[col * 132 + (g << 2) + (c & 3)] = w[idx];
  }
  __syncthreads();
  const int col = tid & 63;
  const int r = blockIdx.x * 8 + ((tid >> 6) << 1);
  const float* r0 = o + (size_t)r * 128;
  const float* r1 = r0 + 128;
  const int wbase = col * 132;
  const int gx = (col >> 3) & 7;
  float a0 = bias[col], a1 = a0;
  for (int c = 0; c < 128; c += 4) {
    const float4 x0 = *(const float4*)&r0[c];
    const float4 x1 = *(const float4*)&r1[c];
    const float4 wv = *(const float4*)&wT[wbase + ((((c >> 2) ^ gx)) << 2)];
    a0 = fmaf(x0.x, wv.x, a0); a0 = fmaf(x0.y, wv.y, a0);
    a0 = fmaf(x0.z, wv.z, a0); a0 = fmaf(x0.w, wv.w, a0);
    a1 = fmaf(x1.x, wv.x, a1); a1 = fmaf(x1.y, wv.y, a1);
    a1 = fmaf(x1.z, wv.z, a1); a1 = fmaf(x1.w, wv.w, a1);
  }
  out[(size_t)r * 64 + col] = a0;
  out[(size_t)(r + 1) * 64 + col] = a1;
}

// ---------------------------------------------------------------------------
extern "C" void kernel_launch(void* const* d_in, const int* in_sizes, int n_in,
                              void* d_out, int out_size, void* d_ws, size_t ws_size,
                              hipStream_t stream) {
  const float* input = (const float*)d_in[0];
  const float* w_qkv = (const float*)d_in[1];
  const float* w_out = (const float*)d_in[2];
  const float* b_out = (const float*)d_in[3];

  char* W = (char*)d_ws;
  float* qf = (float*)(W + 0);
  float* kf = (float*)(W + (4u << 20));   // reused as o fp32 after norm
  ushort* khg = (ushort*)(W + (8u << 20));
  ushort* klg = (ushort*)(W + (10u << 20));
  ushort* vhg = (ushort*)(W + (12u << 20));
  float* psum = (float*)(W + (14u << 20));            // 128 KB
  float* psq = (float*)(W + (14u << 20) + (128u << 10));
  float* qA = (float*)(W + (14u << 20) + (256u << 10));
  float* qB = qA + 256;
  float* ob = kf;  // alias: kf dead after norm_kernel
  float* out = (float*)d_out;

  hipLaunchKernelGGL(qkv_kernel, dim3(768), dim3(256), 0, stream, input, w_qkv, qf, kf,
                     vhg, psum, psq);
  hipLaunchKernelGGL(norm_kernel, dim3(129), dim3(256), 0, stream, kf, khg, klg,
                     psum, psq, qA, qB);
  hipLaunchKernelGGL(attn_kernel, dim3(512), dim3(1024), 0, stream, qf, qA, qB,
                     khg, klg, vhg, ob);
  hipLaunchKernelGGL(proj_kernel, dim3(1024), dim3(256), 0, stream, ob, w_out, b_out, out);
}